// Round 16
// baseline (66.625 us; speedup 1.0000x reference)
//
#include <hip/hip_runtime.h>
#include <math.h>

#define NN 50000
#define FD 128
#define HDIM 256
#define NE 800000
#define NBR_CAP 512
#define M_CAP 8192
#define TT 7
#define TPB 256
#define GB 96              // graph blocks: 96 x 12 = 1152 p-values
#define PSLICE 12
#define GRP 21             // gather groups per block (252 threads used)
#define ECHUNK 2048
#define SBLK 32            // stepper blocks in k_fused (bid 96..127)
#define FGRID (GB + SBLK)
#define SB 32              // k_step blocks
#define SPIN_CAP 50000000

// ws offsets
#define O_NBRCNT   0       // zeroed by 64-B memset node
#define O_MCNT     64
#define O_GDONE    128     // GB u32 -> 512 (zeroed by k_nbr)
#define O_DEG      512     // NN f -> 200512
#define O_BITMAP   200512  // 1568 u32 -> 206784
#define O_ZERO_END 206784  // k_nbr zeroes [O_MCNT, O_ZERO_END)
#define O_NBRNODE  206784  // NBR_CAP i
#define O_NBRW     208832  // NBR_CAP f
#define O_MS       210880  // M_CAP i
#define O_MD       243648  // M_CAP i
#define O_MW       276416  // M_CAP f -> 309184
#define O_GPART    309184  // GB*1024 f -> 702400 (fully overwritten via ssf)
#define O_HBUF     702400  // (TT+1)*HDIM f -> 710592
#define O_CBUF     710592  // (TT+1)*HDIM f -> 718784

__device__ __forceinline__ float sigm(float v) { return 1.f / (1.f + expf(-v)); }
__device__ __forceinline__ float dis_of(float dg) {
    return dg > 0.f ? rsqrtf(fmaxf(dg, 1e-20f)) : 0.f;
}
// System-scope ops execute at the LLC: write-through stores, always-fresh loads.
__device__ __forceinline__ float slf(const float* p) {
    return __hip_atomic_load(p, __ATOMIC_RELAXED, __HIP_MEMORY_SCOPE_SYSTEM);
}
__device__ __forceinline__ void ssf(float* p, float v) {
    __hip_atomic_store(p, v, __ATOMIC_RELAXED, __HIP_MEMORY_SCOPE_SYSTEM);
}

// Scan 1: zero ctrl/deg/bitmap/gdone; collect nbr(0).
__global__ void k_nbr(const int* __restrict__ ei, const float* __restrict__ ew,
                      char* __restrict__ ws) {
    int*   nbrCnt = (int*)(ws + O_NBRCNT);
    int*   nbrNode= (int*)(ws + O_NBRNODE);
    float* nbrW   = (float*)(ws + O_NBRW);

    int gid = blockIdx.x * blockDim.x + threadIdx.x;
    if (gid < (O_ZERO_END - O_MCNT) / 4) ((unsigned*)(ws + O_MCNT))[gid] = 0u;

    int e0 = gid * 4;
    if (e0 >= NE) return;
    int4 d4 = *(const int4*)&ei[NE + e0];
    float4 w4 = *(const float4*)&ew[e0];
    int dd[4] = {d4.x, d4.y, d4.z, d4.w};
    float wv[4] = {w4.x, w4.y, w4.z, w4.w};
    #pragma unroll
    for (int k = 0; k < 4; ++k) {
        if (dd[k] == 0 && wv[k] != 0.f) {
            int s = ei[e0 + k];
            if (s != 0) {
                int slot = atomicAdd(nbrCnt, 1);
                if (slot < NBR_CAP) { nbrNode[slot] = s; nbrW[slot] = wv[k]; }
            }
        }
    }
}

// Scan 2: match edges with d==0 or d in nbr(0); record (s,d,w); mark needed nodes.
__global__ void k_match(const int* __restrict__ ei, const float* __restrict__ ew,
                        char* __restrict__ ws) {
    const int* nbrCnt = (const int*)(ws + O_NBRCNT);
    const int* nbrNode= (const int*)(ws + O_NBRNODE);
    int*      mCnt   = (int*)(ws + O_MCNT);
    int*      mS     = (int*)(ws + O_MS);
    int*      mD     = (int*)(ws + O_MD);
    float*    mW     = (float*)(ws + O_MW);
    unsigned* bitmap = (unsigned*)(ws + O_BITMAP);

    __shared__ int sNode[NBR_CAP];
    __shared__ int sCnt;
    if (threadIdx.x == 0) sCnt = min(*nbrCnt, NBR_CAP);
    __syncthreads();
    int cnt = sCnt;
    for (int i = threadIdx.x; i < cnt; i += blockDim.x) sNode[i] = nbrNode[i];
    __syncthreads();
    if (blockIdx.x == 0 && threadIdx.x == 0) atomicOr(&bitmap[0], 1u);

    int i = blockIdx.x * blockDim.x + threadIdx.x;
    int e0 = i * 4;
    if (e0 >= NE) return;
    int4 s4 = *(const int4*)&ei[e0];
    int4 d4 = *(const int4*)&ei[NE + e0];
    float4 w4 = *(const float4*)&ew[e0];
    int ss[4] = {s4.x, s4.y, s4.z, s4.w};
    int dd[4] = {d4.x, d4.y, d4.z, d4.w};
    float wv[4] = {w4.x, w4.y, w4.z, w4.w};
    bool m[4];
    #pragma unroll
    for (int k = 0; k < 4; ++k) m[k] = (dd[k] == 0);
    for (int j = 0; j < cnt; ++j) {
        int nv = sNode[j];
        #pragma unroll
        for (int k = 0; k < 4; ++k) m[k] |= (dd[k] == nv);
    }
    #pragma unroll
    for (int k = 0; k < 4; ++k) {
        int s = ss[k], d = dd[k];
        float w = wv[k];
        if (s == d || w == 0.f || !m[k]) continue;
        int slot = atomicAdd(mCnt, 1);
        if (slot < M_CAP) { mS[slot] = s; mD[slot] = d; mW[slot] = w; }
        atomicOr(&bitmap[s >> 5], 1u << (s & 31));
        atomicOr(&bitmap[d >> 5], 1u << (d & 31));
    }
}

// Scan 3: deg[s] += w only for bitmap-marked srcs.
__global__ void k_deg(const int* __restrict__ ei, const float* __restrict__ ew,
                      char* __restrict__ ws) {
    const unsigned* bitmap = (const unsigned*)(ws + O_BITMAP);
    float* deg = (float*)(ws + O_DEG);
    int i = blockIdx.x * blockDim.x + threadIdx.x;
    int e0 = i * 4;
    if (e0 >= NE) return;
    int4 s4 = *(const int4*)&ei[e0];
    int4 d4 = *(const int4*)&ei[NE + e0];
    float4 w4 = *(const float4*)&ew[e0];
    int ss[4] = {s4.x, s4.y, s4.z, s4.w};
    int dd[4] = {d4.x, d4.y, d4.z, d4.w};
    float wv[4] = {w4.x, w4.y, w4.z, w4.w};
    #pragma unroll
    for (int k = 0; k < 4; ++k) {
        int s = ss[k];
        if (s == dd[k] || wv[k] == 0.f) continue;
        if (bitmap[s >> 5] & (1u << (s & 31)))
            atomicAdd(&deg[s], wv[k]);
    }
}

// Fused graph + gates. 128 blocks x 256 thr.
// Blocks 0..95: graph slice (coef->gather->tslice->gemv) -> gpart (system stores)
//               -> release gdone[bid] -> exit.
// Blocks 96..127: poll gdone while graph runs; gpart reduce -> gates ->
//               plain-store h0/c0 into hbuf/cbuf slot 0 -> exit.
__global__ __launch_bounds__(TPB) void k_fused(
    const float* __restrict__ x, const float* __restrict__ h, const float* __restrict__ c,
    const float* __restrict__ theta_x, const float* __restrict__ bias_x,
    const float* __restrict__ theta_h, const float* __restrict__ bias_h,
    const float* __restrict__ w_c, const float* __restrict__ b_gate,
    char* __restrict__ ws) {

    const float*  deg    = (const float*)(ws + O_DEG);
    const int*    nbrCnt = (const int*)(ws + O_NBRCNT);
    const int*    mCnt   = (const int*)(ws + O_MCNT);
    const int*    nbrNode= (const int*)(ws + O_NBRNODE);
    const float*  nbrW   = (const float*)(ws + O_NBRW);
    const int*    mS     = (const int*)(ws + O_MS);
    const int*    mD     = (const int*)(ws + O_MD);
    const float*  mW     = (const float*)(ws + O_MW);
    float*        gpart  = (float*)(ws + O_GPART);
    unsigned*     gdone  = (unsigned*)(ws + O_GDONE);
    float*        hbuf   = (float*)(ws + O_HBUF);
    float*        cbuf   = (float*)(ws + O_CBUF);

    __shared__ int   sNode[NBR_CAP];
    __shared__ float sWl[NBR_CAP];
    __shared__ float cf1[ECHUNK], cf2[ECHUNK];
    __shared__ int   sS[ECHUNK];
    __shared__ float tp1[GRP][PSLICE], tp2[GRP][PSLICE];
    __shared__ float tslice[PSLICE];
    __shared__ float sdot[32];
    __shared__ int   sCnt, sMcnt;

    const int tid = threadIdx.x, bid = blockIdx.x;

    if (bid < GB) {
        // ================== graph block ==================
        if (tid == 0) { sCnt = min(*nbrCnt, NBR_CAP); sMcnt = min(*mCnt, M_CAP); }
        __syncthreads();
        const int ncnt = sCnt, mcnt = sMcnt;
        for (int i = tid; i < ncnt; i += TPB) { sNode[i] = nbrNode[i]; sWl[i] = nbrW[i]; }
        __syncthreads();

        const bool isx = bid < 32;                     // 384 x-rows, 768 h-rows
        const int qstart = bid * PSLICE - (isx ? 0 : 3 * FD);
        const float* fb0 = isx ? x : h;
        const int fstride = isx ? FD : HDIM;

        const int pl = tid % PSLICE, gr = tid / PSLICE;
        const float* fbase = fb0 + (qstart + pl) % fstride;
        const float dis0 = dis_of(deg[0]);

        float a1 = 0.f, a2 = 0.f;
        for (int c0i = 0; c0i < mcnt; c0i += ECHUNK) {
            int clen = min(ECHUNK, mcnt - c0i);
            for (int i = tid; i < clen; i += TPB) {    // inline per-edge coefs
                int sI = mS[c0i + i], dI = mD[c0i + i];
                float w = mW[c0i + i];
                float disd = dis_of(deg[dI]);
                float wn = dis_of(deg[sI]) * w * disd;
                float Wd = 0.f;
                for (int j = 0; j < ncnt; ++j) Wd += (sNode[j] == dI) ? sWl[j] : 0.f;
                cf1[i] = (dI == 0) ? wn : 0.f;
                cf2[i] = wn * (dis0 * disd * Wd);
                sS[i] = sI;
            }
            __syncthreads();
            if (gr < GRP) {                            // 4-deep pipelined gather
                int i = gr;
                for (; i + 3 * GRP < clen; i += 4 * GRP) {
                    int s0 = sS[i], s1 = sS[i + GRP], s2 = sS[i + 2 * GRP], s3 = sS[i + 3 * GRP];
                    float c10 = cf1[i], c11 = cf1[i + GRP], c12 = cf1[i + 2 * GRP], c13 = cf1[i + 3 * GRP];
                    float c20 = cf2[i], c21 = cf2[i + GRP], c22 = cf2[i + 2 * GRP], c23 = cf2[i + 3 * GRP];
                    float v0 = fbase[(size_t)s0 * fstride];
                    float v1 = fbase[(size_t)s1 * fstride];
                    float v2 = fbase[(size_t)s2 * fstride];
                    float v3 = fbase[(size_t)s3 * fstride];
                    a1 += c10 * v0 + c11 * v1 + c12 * v2 + c13 * v3;
                    a2 += c20 * v0 + c21 * v1 + c22 * v2 + c23 * v3;
                }
                for (; i < clen; i += GRP) {
                    float v = fbase[(size_t)sS[i] * fstride];
                    a1 += cf1[i] * v;
                    a2 += cf2[i] * v;
                }
            }
            __syncthreads();
        }
        if (gr < GRP) { tp1[gr][pl] = a1; tp2[gr][pl] = a2; }
        __syncthreads();
        if (tid < PSLICE) {
            float A1 = 0.f, A2 = 0.f;
            #pragma unroll
            for (int g2 = 0; g2 < GRP; ++g2) { A1 += tp1[g2][tid]; A2 += tp2[g2][tid]; }
            int q = qstart + tid;
            int ko = q / fstride;
            float ff0 = fb0[q % fstride];
            tslice[tid] = (ko == 0) ? ff0 : ((ko == 1) ? -A1 : 2.f * A2 - ff0);
        }
        __syncthreads();

        {   // gemv over the block's 12 p-rows; system-scope stores to gpart
            const float* tb = isx ? theta_x : theta_h;
            const size_t gs = isx ? (size_t)(3 * FD) * HDIM : (size_t)(3 * HDIM) * HDIM;
            float g0 = 0.f, g1 = 0.f, g2v = 0.f, g3 = 0.f;
            #pragma unroll
            for (int pp = 0; pp < PSLICE; ++pp) {
                float tv = tslice[pp];
                const float* row = tb + (size_t)(qstart + pp) * HDIM;
                g0  += tv * row[tid];
                g1  += tv * row[gs + tid];
                g2v += tv * row[2 * gs + tid];
                g3  += tv * row[3 * gs + tid];
            }
            float* gp = gpart + (size_t)bid * 1024;
            ssf(&gp[tid], g0);
            ssf(&gp[HDIM + tid], g1);
            ssf(&gp[2 * HDIM + tid], g2v);
            ssf(&gp[3 * HDIM + tid], g3);
        }
        __syncthreads();   // drains vmcnt: all this block's gpart stores at LLC
        if (tid == 0)
            __hip_atomic_store(&gdone[bid], 1u, __ATOMIC_RELEASE, __HIP_MEMORY_SCOPE_SYSTEM);
        return;
    }

    // ================== gates block ==================
    const int sbid = bid - GB;

    // poll graph-done flags while the graph still runs (96 parallel pollers)
    if (tid < GB) {
        int sp = 0;
        while (__hip_atomic_load(&gdone[tid], __ATOMIC_RELAXED,
                                 __HIP_MEMORY_SCOPE_SYSTEM) == 0u) {
            if (++sp > SPIN_CAP) break;
        }
    }
    __syncthreads();       // all 96 flags observed -> all gpart data at LLC

    // gpart reduce for this block's 32 gate-dims: d = tid>>3, 8 threads/dim
    {
        const int d = tid >> 3, j = tid & 7;
        const int g = d >> 3, kk = d & 7, o = sbid * 8 + kk;
        float s = 0.f;
        #pragma unroll
        for (int pb = j; pb < GB; pb += 8) s += slf(&gpart[(size_t)pb * 1024 + g * HDIM + o]);
        s += __shfl_down(s, 4);
        s += __shfl_down(s, 2);
        s += __shfl_down(s, 1);
        if (j == 0) sdot[d] = s;
    }
    __syncthreads();

    // gates for this block's 8 dims -> hbuf/cbuf slot 0 (plain stores)
    if (tid < 8) {
        const int o = sbid * 8 + tid;
        float g0 = sdot[tid]      + bias_x[o]            + bias_h[o];
        float g1 = sdot[8 + tid]  + bias_x[HDIM + o]     + bias_h[HDIM + o];
        float g2 = sdot[16 + tid] + bias_x[2 * HDIM + o] + bias_h[2 * HDIM + o];
        float g3 = sdot[24 + tid] + bias_x[3 * HDIM + o] + bias_h[3 * HDIM + o];
        float c0 = c[o];
        float I  = sigm(g0 + w_c[o] * c0 + b_gate[o]);
        float Fg = sigm(g1 + w_c[HDIM + o] * c0 + b_gate[HDIM + o]);
        float Cn = Fg * c0 + I * tanhf(g2 + b_gate[2 * HDIM + o]);
        float O  = sigm(g3 + w_c[2 * HDIM + o] * Cn + b_gate[3 * HDIM + o]);
        hbuf[o] = O * tanhf(Cn);
        cbuf[o] = Cn;
    }
}

// One LSTM step (t arg). 32 blocks x 256 threads, pure dataflow:
// reads hbuf/cbuf slot t, writes slot t+1; block b owns dims [b*8, b*8+8).
// sinp (= out[t-1] for t>=1) computed redundantly per block; block 0 stores it.
__global__ __launch_bounds__(TPB) void k_step(
    int t, const float* __restrict__ x,
    const float* __restrict__ w_ih, const float* __restrict__ w_hh,
    const float* __restrict__ b_ih, const float* __restrict__ b_hh,
    const float* __restrict__ w_out, const float* __restrict__ b_out,
    float* __restrict__ out, char* __restrict__ ws) {

    float* hbuf = (float*)(ws + O_HBUF);
    float* cbuf = (float*)(ws + O_CBUF);

    __shared__ __align__(16) float sh[HDIM];
    __shared__ float sdot[32];
    __shared__ float swsum[4];

    const int tid = threadIdx.x, bid = blockIdx.x;
    const float* hr = hbuf + t * HDIM;

    // full h(t) -> LDS (coalesced), plus per-thread w_out product for sinp
    float hv = hr[tid];
    sh[tid] = hv;
    float pw = hv * w_out[tid];
    pw += __shfl_down(pw, 32);
    pw += __shfl_down(pw, 16);
    pw += __shfl_down(pw, 8);
    pw += __shfl_down(pw, 4);
    pw += __shfl_down(pw, 2);
    pw += __shfl_down(pw, 1);
    if ((tid & 63) == 0) swsum[tid >> 6] = pw;
    __syncthreads();
    const float bo = b_out[0];
    const float sval = swsum[0] + swsum[1] + swsum[2] + swsum[3] + bo; // = out[t-1]
    const float sinp = (t == 0) ? x[FD - 1] : sval;
    if (t > 0 && bid == 0 && tid == 0) out[t - 1] = sval;

    // dot: 32 rows/block, 8 lanes/row x 32 FMA
    const int rl = tid >> 3, seg = tid & 7;
    const int grow = (rl >> 3) * HDIM + bid * 8 + (rl & 7);
    const float* wrow = w_hh + (size_t)grow * HDIM + seg * 32;
    const float* shh = &sh[seg * 32];
    float acc = 0.f;
    #pragma unroll
    for (int k = 0; k < 8; ++k) {
        float4 wv = *(const float4*)&wrow[k * 4];
        float4 hv4 = *(const float4*)&shh[k * 4];
        acc += hv4.x * wv.x + hv4.y * wv.y + hv4.z * wv.z + hv4.w * wv.w;
    }
    acc += __shfl_down(acc, 4);
    acc += __shfl_down(acc, 2);
    acc += __shfl_down(acc, 1);
    if (seg == 0) sdot[rl] = acc + sinp * w_ih[grow] + b_ih[grow] + b_hh[grow];
    __syncthreads();

    if (tid < 8) {
        const int dim = bid * 8 + tid;
        float cd = cbuf[t * HDIM + dim];
        float iv = sdot[tid], fv = sdot[8 + tid], gv = sdot[16 + tid], ov = sdot[24 + tid];
        float cn = sigm(fv) * cd + sigm(iv) * tanhf(gv);
        float hn = sigm(ov) * tanhf(cn);
        hbuf[(t + 1) * HDIM + dim] = hn;
        cbuf[(t + 1) * HDIM + dim] = cn;
    }
}

// Final: out[TT-1] from hbuf slot TT.
__global__ void k_fin(const float* __restrict__ w_out, const float* __restrict__ b_out,
                      float* __restrict__ out, char* __restrict__ ws) {
    const float* hr = (const float*)(ws + O_HBUF) + TT * HDIM;
    const int tid = threadIdx.x;            // 64 lanes
    float pw = 0.f;
    #pragma unroll
    for (int j = 0; j < 4; ++j) pw += hr[tid * 4 + j] * w_out[tid * 4 + j];
    pw += __shfl_down(pw, 32);
    pw += __shfl_down(pw, 16);
    pw += __shfl_down(pw, 8);
    pw += __shfl_down(pw, 4);
    pw += __shfl_down(pw, 2);
    pw += __shfl_down(pw, 1);
    if (tid == 0) out[TT - 1] = pw + b_out[0];
}

extern "C" void kernel_launch(void* const* d_in, const int* in_sizes, int n_in,
                              void* d_out, int out_size, void* d_ws, size_t ws_size,
                              hipStream_t stream) {
    const float* x       = (const float*)d_in[0];
    const int*   ei      = (const int*)d_in[1];
    const float* ew      = (const float*)d_in[2];
    const float* h       = (const float*)d_in[3];
    const float* c       = (const float*)d_in[4];
    const float* theta_x = (const float*)d_in[5];
    const float* bias_x  = (const float*)d_in[6];
    const float* theta_h = (const float*)d_in[7];
    const float* bias_h  = (const float*)d_in[8];
    const float* w_c     = (const float*)d_in[9];
    const float* b_gate  = (const float*)d_in[10];
    const float* w_ih    = (const float*)d_in[11];
    const float* w_hh    = (const float*)d_in[12];
    const float* b_ih    = (const float*)d_in[13];
    const float* b_hh    = (const float*)d_in[14];
    const float* w_out   = (const float*)d_in[15];
    const float* b_out   = (const float*)d_in[16];
    char* ws = (char*)d_ws;
    float* out = (float*)d_out;

    hipMemsetAsync(ws, 0, 64, stream);          // nbrCnt; rest zeroed by k_nbr

    int eb4 = (NE / 4 + TPB - 1) / TPB;         // 782 blocks
    k_nbr<<<eb4, TPB, 0, stream>>>(ei, ew, ws);
    k_match<<<eb4, TPB, 0, stream>>>(ei, ew, ws);
    k_deg<<<eb4, TPB, 0, stream>>>(ei, ew, ws);
    k_fused<<<FGRID, TPB, 0, stream>>>(x, h, c, theta_x, bias_x, theta_h, bias_h,
                                       w_c, b_gate, ws);
    for (int t = 0; t < TT; ++t)
        k_step<<<SB, TPB, 0, stream>>>(t, x, w_ih, w_hh, b_ih, b_hh, w_out, b_out, out, ws);
    k_fin<<<1, 64, 0, stream>>>(w_out, b_out, out, ws);
}

// Round 17
// 59.333 us; speedup vs baseline: 1.1229x; 1.1229x over previous
//
#include <hip/hip_runtime.h>
#include <math.h>

#define NN 50000
#define FD 128
#define HDIM 256
#define NE 800000
#define NBR_CAP 512
#define M_CAP 8192
#define TT 7
#define TPB 256
#define GB 96              // k_graph blocks: 96 x 12 = 1152 p-values
#define PSLICE 12
#define GRP 21             // gather groups per block (252 threads used)
#define ECHUNK 2048
#define SB 32              // k_tail2 blocks
#define SPIN_CAP 50000000

// ws offsets
#define O_NBRCNT   0       // zeroed by 64-B memset node
#define O_MCNT     64
#define O_HFLAG    128     // (TT+1)*32 flags x 64B line = 16384 -> 16512
#define O_HPAY     16512   // (TT+1)*HDIM f = 8192 -> 24704
#define O_DEG      24704   // NN f -> 224704
#define O_BITMAP   224704  // 1568 u32 -> 230976
#define O_ZERO_END 230976  // k_nbr zeroes [O_MCNT, O_ZERO_END)
#define O_NBRNODE  230976  // NBR_CAP i
#define O_NBRW     233024  // NBR_CAP f
#define O_MS       235072  // M_CAP i
#define O_MD       267840  // M_CAP i
#define O_MW       300608  // M_CAP f -> 333376
#define O_GPART    333376  // GB*1024 f -> 726592 (fully overwritten, no zero)

__device__ __forceinline__ float sigm(float v) { return 1.f / (1.f + expf(-v)); }
__device__ __forceinline__ float dis_of(float dg) {
    return dg > 0.f ? rsqrtf(fmaxf(dg, 1e-20f)) : 0.f;
}
// System-scope ops execute at the LLC (bypass L1 + per-XCD L2).
__device__ __forceinline__ float slf(const float* p) {
    return __hip_atomic_load(p, __ATOMIC_RELAXED, __HIP_MEMORY_SCOPE_SYSTEM);
}
__device__ __forceinline__ void ssf(float* p, float v) {
    __hip_atomic_store(p, v, __ATOMIC_RELAXED, __HIP_MEMORY_SCOPE_SYSTEM);
}

// Scan 1: zero ctrl/flags/payload/deg/bitmap; collect nbr(0).
__global__ void k_nbr(const int* __restrict__ ei, const float* __restrict__ ew,
                      char* __restrict__ ws) {
    int*   nbrCnt = (int*)(ws + O_NBRCNT);
    int*   nbrNode= (int*)(ws + O_NBRNODE);
    float* nbrW   = (float*)(ws + O_NBRW);

    int gid = blockIdx.x * blockDim.x + threadIdx.x;
    if (gid < (O_ZERO_END - O_MCNT) / 4) ((unsigned*)(ws + O_MCNT))[gid] = 0u;

    int e0 = gid * 4;
    if (e0 >= NE) return;
    int4 d4 = *(const int4*)&ei[NE + e0];
    float4 w4 = *(const float4*)&ew[e0];
    int dd[4] = {d4.x, d4.y, d4.z, d4.w};
    float wv[4] = {w4.x, w4.y, w4.z, w4.w};
    #pragma unroll
    for (int k = 0; k < 4; ++k) {
        if (dd[k] == 0 && wv[k] != 0.f) {
            int s = ei[e0 + k];
            if (s != 0) {
                int slot = atomicAdd(nbrCnt, 1);
                if (slot < NBR_CAP) { nbrNode[slot] = s; nbrW[slot] = wv[k]; }
            }
        }
    }
}

// Scan 2: match edges with d==0 or d in nbr(0); record (s,d,w); mark needed nodes.
__global__ void k_match(const int* __restrict__ ei, const float* __restrict__ ew,
                        char* __restrict__ ws) {
    const int* nbrCnt = (const int*)(ws + O_NBRCNT);
    const int* nbrNode= (const int*)(ws + O_NBRNODE);
    int*      mCnt   = (int*)(ws + O_MCNT);
    int*      mS     = (int*)(ws + O_MS);
    int*      mD     = (int*)(ws + O_MD);
    float*    mW     = (float*)(ws + O_MW);
    unsigned* bitmap = (unsigned*)(ws + O_BITMAP);

    __shared__ int sNode[NBR_CAP];
    __shared__ int sCnt;
    if (threadIdx.x == 0) sCnt = min(*nbrCnt, NBR_CAP);
    __syncthreads();
    int cnt = sCnt;
    for (int i = threadIdx.x; i < cnt; i += blockDim.x) sNode[i] = nbrNode[i];
    __syncthreads();
    if (blockIdx.x == 0 && threadIdx.x == 0) atomicOr(&bitmap[0], 1u);

    int i = blockIdx.x * blockDim.x + threadIdx.x;
    int e0 = i * 4;
    if (e0 >= NE) return;
    int4 s4 = *(const int4*)&ei[e0];
    int4 d4 = *(const int4*)&ei[NE + e0];
    float4 w4 = *(const float4*)&ew[e0];
    int ss[4] = {s4.x, s4.y, s4.z, s4.w};
    int dd[4] = {d4.x, d4.y, d4.z, d4.w};
    float wv[4] = {w4.x, w4.y, w4.z, w4.w};
    bool m[4];
    #pragma unroll
    for (int k = 0; k < 4; ++k) m[k] = (dd[k] == 0);
    for (int j = 0; j < cnt; ++j) {
        int nv = sNode[j];
        #pragma unroll
        for (int k = 0; k < 4; ++k) m[k] |= (dd[k] == nv);
    }
    #pragma unroll
    for (int k = 0; k < 4; ++k) {
        int s = ss[k], d = dd[k];
        float w = wv[k];
        if (s == d || w == 0.f || !m[k]) continue;
        int slot = atomicAdd(mCnt, 1);
        if (slot < M_CAP) { mS[slot] = s; mD[slot] = d; mW[slot] = w; }
        atomicOr(&bitmap[s >> 5], 1u << (s & 31));
        atomicOr(&bitmap[d >> 5], 1u << (d & 31));
    }
}

// Scan 3: deg[s] += w only for bitmap-marked srcs.
__global__ void k_deg(const int* __restrict__ ei, const float* __restrict__ ew,
                      char* __restrict__ ws) {
    const unsigned* bitmap = (const unsigned*)(ws + O_BITMAP);
    float* deg = (float*)(ws + O_DEG);
    int i = blockIdx.x * blockDim.x + threadIdx.x;
    int e0 = i * 4;
    if (e0 >= NE) return;
    int4 s4 = *(const int4*)&ei[e0];
    int4 d4 = *(const int4*)&ei[NE + e0];
    float4 w4 = *(const float4*)&ew[e0];
    int ss[4] = {s4.x, s4.y, s4.z, s4.w};
    int dd[4] = {d4.x, d4.y, d4.z, d4.w};
    float wv[4] = {w4.x, w4.y, w4.z, w4.w};
    #pragma unroll
    for (int k = 0; k < 4; ++k) {
        int s = ss[k];
        if (s == dd[k] || wv[k] == 0.f) continue;
        if (bitmap[s >> 5] & (1u << (s & 31)))
            atomicAdd(&deg[s], wv[k]);
    }
}

// Graph: 96 blocks x 256 thr. Inline coef -> 4-deep pipelined gather ->
// tslice -> gemv partials -> gpart (plain stores; kernel boundary = coherence).
__global__ __launch_bounds__(TPB) void k_graph(
    const float* __restrict__ x, const float* __restrict__ h,
    const float* __restrict__ theta_x, const float* __restrict__ theta_h,
    char* __restrict__ ws) {

    const float* deg    = (const float*)(ws + O_DEG);
    const int*   nbrCnt = (const int*)(ws + O_NBRCNT);
    const int*   mCnt   = (const int*)(ws + O_MCNT);
    const int*   nbrNode= (const int*)(ws + O_NBRNODE);
    const float* nbrW   = (const float*)(ws + O_NBRW);
    const int*   mS     = (const int*)(ws + O_MS);
    const int*   mD     = (const int*)(ws + O_MD);
    const float* mW     = (const float*)(ws + O_MW);
    float*       gpart  = (float*)(ws + O_GPART);

    __shared__ int   sNode[NBR_CAP];
    __shared__ float sWl[NBR_CAP];
    __shared__ float cf1[ECHUNK], cf2[ECHUNK];
    __shared__ int   sS[ECHUNK];
    __shared__ float tp1[GRP][PSLICE], tp2[GRP][PSLICE];
    __shared__ float tslice[PSLICE];
    __shared__ int   sCnt, sMcnt;

    const int tid = threadIdx.x, bid = blockIdx.x;
    if (tid == 0) { sCnt = min(*nbrCnt, NBR_CAP); sMcnt = min(*mCnt, M_CAP); }
    __syncthreads();
    const int ncnt = sCnt, mcnt = sMcnt;
    for (int i = tid; i < ncnt; i += TPB) { sNode[i] = nbrNode[i]; sWl[i] = nbrW[i]; }
    __syncthreads();

    const bool isx = bid < 32;                         // 384 x-rows, 768 h-rows
    const int qstart = bid * PSLICE - (isx ? 0 : 3 * FD);
    const float* fb0 = isx ? x : h;
    const int fstride = isx ? FD : HDIM;

    const int pl = tid % PSLICE, gr = tid / PSLICE;
    const float* fbase = fb0 + (qstart + pl) % fstride;
    const float dis0 = dis_of(deg[0]);

    float a1 = 0.f, a2 = 0.f;
    for (int c0i = 0; c0i < mcnt; c0i += ECHUNK) {
        int clen = min(ECHUNK, mcnt - c0i);
        for (int i = tid; i < clen; i += TPB) {        // inline per-edge coefs
            int sI = mS[c0i + i], dI = mD[c0i + i];
            float w = mW[c0i + i];
            float disd = dis_of(deg[dI]);
            float wn = dis_of(deg[sI]) * w * disd;
            float Wd = 0.f;
            for (int j = 0; j < ncnt; ++j) Wd += (sNode[j] == dI) ? sWl[j] : 0.f;
            cf1[i] = (dI == 0) ? wn : 0.f;
            cf2[i] = wn * (dis0 * disd * Wd);
            sS[i] = sI;
        }
        __syncthreads();
        if (gr < GRP) {                                // 4-deep pipelined gather
            int i = gr;
            for (; i + 3 * GRP < clen; i += 4 * GRP) {
                int s0 = sS[i], s1 = sS[i + GRP], s2 = sS[i + 2 * GRP], s3 = sS[i + 3 * GRP];
                float c10 = cf1[i], c11 = cf1[i + GRP], c12 = cf1[i + 2 * GRP], c13 = cf1[i + 3 * GRP];
                float c20 = cf2[i], c21 = cf2[i + GRP], c22 = cf2[i + 2 * GRP], c23 = cf2[i + 3 * GRP];
                float v0 = fbase[(size_t)s0 * fstride];
                float v1 = fbase[(size_t)s1 * fstride];
                float v2 = fbase[(size_t)s2 * fstride];
                float v3 = fbase[(size_t)s3 * fstride];
                a1 += c10 * v0 + c11 * v1 + c12 * v2 + c13 * v3;
                a2 += c20 * v0 + c21 * v1 + c22 * v2 + c23 * v3;
            }
            for (; i < clen; i += GRP) {
                float v = fbase[(size_t)sS[i] * fstride];
                a1 += cf1[i] * v;
                a2 += cf2[i] * v;
            }
        }
        __syncthreads();
    }
    if (gr < GRP) { tp1[gr][pl] = a1; tp2[gr][pl] = a2; }
    __syncthreads();
    if (tid < PSLICE) {
        float A1 = 0.f, A2 = 0.f;
        #pragma unroll
        for (int g2 = 0; g2 < GRP; ++g2) { A1 += tp1[g2][tid]; A2 += tp2[g2][tid]; }
        int q = qstart + tid;
        int ko = q / fstride;
        float ff0 = fb0[q % fstride];
        tslice[tid] = (ko == 0) ? ff0 : ((ko == 1) ? -A1 : 2.f * A2 - ff0);
    }
    __syncthreads();

    {   // gemv over the block's 12 p-rows; plain stores to gpart
        const float* tb = isx ? theta_x : theta_h;
        const size_t gs = isx ? (size_t)(3 * FD) * HDIM : (size_t)(3 * HDIM) * HDIM;
        float g0 = 0.f, g1 = 0.f, g2v = 0.f, g3 = 0.f;
        #pragma unroll
        for (int pp = 0; pp < PSLICE; ++pp) {
            float tv = tslice[pp];
            const float* row = tb + (size_t)(qstart + pp) * HDIM;
            g0  += tv * row[tid];
            g1  += tv * row[gs + tid];
            g2v += tv * row[2 * gs + tid];
            g3  += tv * row[3 * gs + tid];
        }
        float* gp = gpart + (size_t)bid * 1024;
        gp[tid] = g0;
        gp[HDIM + tid] = g1;
        gp[2 * HDIM + tid] = g2v;
        gp[3 * HDIM + tid] = g3;
    }
}

// Tail: 32 blocks x 256 thr. gpart reduce -> gates -> 7 steps.
// Per-round exchange: producer wave stores 8 floats (one 64B payload line) then
// ONE release flag-store to a padded private flag line; 32 consumer threads poll
// one flag line each (low contention); after syncthreads all threads single-shot
// load the payload (at LLC before the flag, by release ordering).
__global__ __launch_bounds__(TPB) void k_tail2(
    const float* __restrict__ x, const float* __restrict__ c,
    const float* __restrict__ bias_x, const float* __restrict__ bias_h,
    const float* __restrict__ w_c, const float* __restrict__ b_gate,
    const float* __restrict__ w_ih, const float* __restrict__ w_hh,
    const float* __restrict__ b_ih, const float* __restrict__ b_hh,
    const float* __restrict__ w_out, const float* __restrict__ b_out,
    float* __restrict__ out, char* __restrict__ ws) {

    unsigned* hflag = (unsigned*)(ws + O_HFLAG);   // [(t*32+b)*16] padded lines
    float*    hpay  = (float*)(ws + O_HPAY);       // [t*HDIM + dim]
    const float* gpart = (const float*)(ws + O_GPART);

    __shared__ __align__(16) float sh[HDIM];
    __shared__ float sdot[32];
    __shared__ float swsum[4];

    const int tid = threadIdx.x, bid = blockIdx.x;

    // w_hh rows in VGPRs (proven no-spill layout: 32 rows/block, 8 thr/row)
    const int rl = tid >> 3, seg = tid & 7;
    const int grow = (rl >> 3) * HDIM + bid * 8 + (rl & 7);
    float4 wreg[8];
    #pragma unroll
    for (int k = 0; k < 8; ++k)
        wreg[k] = *(const float4*)&w_hh[(size_t)grow * HDIM + seg * 32 + k * 4];
    const float wih_r = w_ih[grow];
    const float br    = b_ih[grow] + b_hh[grow];
    const float bo    = b_out[0];
    const float wout_r = w_out[tid];

    // gpart reduce for this block's 32 gate-dims: d = tid>>3, 8 threads/dim
    {
        const int d = tid >> 3, j = tid & 7;
        const int g = d >> 3, kk = d & 7, o = bid * 8 + kk;
        float s = 0.f;
        #pragma unroll
        for (int pb = j; pb < GB; pb += 8) s += gpart[(size_t)pb * 1024 + g * HDIM + o];
        s += __shfl_down(s, 4);
        s += __shfl_down(s, 2);
        s += __shfl_down(s, 1);
        if (j == 0) sdot[d] = s;
    }
    __syncthreads();

    // gates -> payload slot 0 + flag; c0 in creg
    float creg = 0.f;
    if (tid < 8) {
        const int o = bid * 8 + tid;
        float g0 = sdot[tid]      + bias_x[o]            + bias_h[o];
        float g1 = sdot[8 + tid]  + bias_x[HDIM + o]     + bias_h[HDIM + o];
        float g2 = sdot[16 + tid] + bias_x[2 * HDIM + o] + bias_h[2 * HDIM + o];
        float g3 = sdot[24 + tid] + bias_x[3 * HDIM + o] + bias_h[3 * HDIM + o];
        float c0 = c[o];
        float I  = sigm(g0 + w_c[o] * c0 + b_gate[o]);
        float Fg = sigm(g1 + w_c[HDIM + o] * c0 + b_gate[HDIM + o]);
        float Cn = Fg * c0 + I * tanhf(g2 + b_gate[2 * HDIM + o]);
        float O  = sigm(g3 + w_c[2 * HDIM + o] * Cn + b_gate[3 * HDIM + o]);
        creg = Cn;
        ssf(&hpay[o], O * tanhf(Cn));
    }
    if (tid == 0)   // same wave as payload stores: release orders them first
        __hip_atomic_store(&hflag[bid * 16], 1u, __ATOMIC_RELEASE,
                           __HIP_MEMORY_SCOPE_SYSTEM);
    if (tid < SB) { // 32 pollers, one private flag line each
        int sp = 0;
        while (__hip_atomic_load(&hflag[tid * 16], __ATOMIC_ACQUIRE,
                                 __HIP_MEMORY_SCOPE_SYSTEM) == 0u)
            if (++sp > SPIN_CAP) break;
    }
    __syncthreads();
    sh[tid] = slf(&hpay[tid]);
    __syncthreads();
    float sinp = x[FD - 1];

    for (int t = 0; t < TT; ++t) {
        // dot on sh = h(t)
        float acc = 0.f;
        const float* shh = &sh[seg * 32];
        #pragma unroll
        for (int k = 0; k < 8; ++k) {
            float4 hv = *(const float4*)&shh[k * 4];
            acc += hv.x * wreg[k].x + hv.y * wreg[k].y + hv.z * wreg[k].z + hv.w * wreg[k].w;
        }
        acc += __shfl_down(acc, 4);
        acc += __shfl_down(acc, 2);
        acc += __shfl_down(acc, 1);
        if (seg == 0) sdot[rl] = acc + sinp * wih_r + br;
        __syncthreads();                        // S1: sh reads done, sdot ready
        if (tid < 8) {
            float iv = sdot[tid], fv = sdot[8 + tid], gv = sdot[16 + tid], ov = sdot[24 + tid];
            float cn = sigm(fv) * creg + sigm(iv) * tanhf(gv);
            float hn = sigm(ov) * tanhf(cn);
            creg = cn;
            ssf(&hpay[(t + 1) * HDIM + bid * 8 + tid], hn);
        }
        if (tid == 0)
            __hip_atomic_store(&hflag[((t + 1) * SB + bid) * 16], 1u, __ATOMIC_RELEASE,
                               __HIP_MEMORY_SCOPE_SYSTEM);
        if (tid < SB) {
            int sp = 0;
            while (__hip_atomic_load(&hflag[((t + 1) * SB + tid) * 16], __ATOMIC_ACQUIRE,
                                     __HIP_MEMORY_SCOPE_SYSTEM) == 0u)
                if (++sp > SPIN_CAP) break;
        }
        __syncthreads();                        // all 32 flags seen by the block
        float hval = slf(&hpay[(t + 1) * HDIM + tid]);
        sh[tid] = hval;
        float pw = wout_r * hval;               // out[t] = w_out . h(t+1) + bo
        pw += __shfl_down(pw, 32);
        pw += __shfl_down(pw, 16);
        pw += __shfl_down(pw, 8);
        pw += __shfl_down(pw, 4);
        pw += __shfl_down(pw, 2);
        pw += __shfl_down(pw, 1);
        if ((tid & 63) == 0) swsum[tid >> 6] = pw;
        __syncthreads();                        // S2: swsum + new sh visible
        float sval = swsum[0] + swsum[1] + swsum[2] + swsum[3] + bo;
        sinp = sval;                            // input to step t+1
        if (bid == 0 && tid == 0) out[t] = sval;
    }
}

extern "C" void kernel_launch(void* const* d_in, const int* in_sizes, int n_in,
                              void* d_out, int out_size, void* d_ws, size_t ws_size,
                              hipStream_t stream) {
    const float* x       = (const float*)d_in[0];
    const int*   ei      = (const int*)d_in[1];
    const float* ew      = (const float*)d_in[2];
    const float* h       = (const float*)d_in[3];
    const float* c       = (const float*)d_in[4];
    const float* theta_x = (const float*)d_in[5];
    const float* bias_x  = (const float*)d_in[6];
    const float* theta_h = (const float*)d_in[7];
    const float* bias_h  = (const float*)d_in[8];
    const float* w_c     = (const float*)d_in[9];
    const float* b_gate  = (const float*)d_in[10];
    const float* w_ih    = (const float*)d_in[11];
    const float* w_hh    = (const float*)d_in[12];
    const float* b_ih    = (const float*)d_in[13];
    const float* b_hh    = (const float*)d_in[14];
    const float* w_out   = (const float*)d_in[15];
    const float* b_out   = (const float*)d_in[16];
    char* ws = (char*)d_ws;
    float* out = (float*)d_out;

    hipMemsetAsync(ws, 0, 64, stream);          // nbrCnt; rest zeroed by k_nbr

    int eb4 = (NE / 4 + TPB - 1) / TPB;         // 782 blocks
    k_nbr<<<eb4, TPB, 0, stream>>>(ei, ew, ws);
    k_match<<<eb4, TPB, 0, stream>>>(ei, ew, ws);
    k_deg<<<eb4, TPB, 0, stream>>>(ei, ew, ws);
    k_graph<<<GB, TPB, 0, stream>>>(x, h, theta_x, theta_h, ws);
    k_tail2<<<SB, TPB, 0, stream>>>(x, c, bias_x, bias_h, w_c, b_gate,
                                    w_ih, w_hh, b_ih, b_hh, w_out, b_out, out, ws);
}

// Round 18
// 56.116 us; speedup vs baseline: 1.1873x; 1.0573x over previous
//
#include <hip/hip_runtime.h>
#include <math.h>

#define NN 50000
#define FD 128
#define HDIM 256
#define NE 800000
#define NBR_CAP 512
#define M_CAP 8192
#define TT 7
#define TPB 256
#define GB 96              // k_graph blocks: 96 x 12 = 1152 p-values
#define PSLICE 12
#define GRP 21             // gather groups per block (252 threads used)
#define ECHUNK 2048
#define SB 32              // k_tail2 blocks
#define SPIN_CAP 50000000

// ws offsets
#define O_NBRCNT   0       // zeroed by 64-B memset node
#define O_MCNT     64
#define O_HSYNC    128     // (TT+1)*256 dims x 32B slot = 65536 -> 65664
#define O_DEG      65664   // NN f -> 265664
#define O_BITMAP   265664  // 1568 u32 -> 271936
#define O_ZERO_END 271936  // k_nbr zeroes [O_MCNT, O_ZERO_END)
#define O_NBRNODE  271936  // NBR_CAP i
#define O_NBRW     273984  // NBR_CAP f
#define O_MS       276032  // M_CAP i
#define O_MD       308800  // M_CAP i
#define O_MW       341568  // M_CAP f -> 374336
#define O_GPART    374336  // GB*1024 f -> 767552 (fully overwritten, no zero)

__device__ __forceinline__ float sigm(float v) { return 1.f / (1.f + expf(-v)); }
__device__ __forceinline__ float dis_of(float dg) {
    return dg > 0.f ? rsqrtf(fmaxf(dg, 1e-20f)) : 0.f;
}

// Scan 1: zero ctrl/hsync/deg/bitmap; collect nbr(0).
__global__ void k_nbr(const int* __restrict__ ei, const float* __restrict__ ew,
                      char* __restrict__ ws) {
    int*   nbrCnt = (int*)(ws + O_NBRCNT);
    int*   nbrNode= (int*)(ws + O_NBRNODE);
    float* nbrW   = (float*)(ws + O_NBRW);

    int gid = blockIdx.x * blockDim.x + threadIdx.x;
    if (gid < (O_ZERO_END - O_MCNT) / 4) ((unsigned*)(ws + O_MCNT))[gid] = 0u;

    int e0 = gid * 4;
    if (e0 >= NE) return;
    int4 d4 = *(const int4*)&ei[NE + e0];
    float4 w4 = *(const float4*)&ew[e0];
    int dd[4] = {d4.x, d4.y, d4.z, d4.w};
    float wv[4] = {w4.x, w4.y, w4.z, w4.w};
    #pragma unroll
    for (int k = 0; k < 4; ++k) {
        if (dd[k] == 0 && wv[k] != 0.f) {
            int s = ei[e0 + k];
            if (s != 0) {
                int slot = atomicAdd(nbrCnt, 1);
                if (slot < NBR_CAP) { nbrNode[slot] = s; nbrW[slot] = wv[k]; }
            }
        }
    }
}

// Scan 2: match edges with d==0 or d in nbr(0); record (s,d,w); mark needed nodes.
__global__ void k_match(const int* __restrict__ ei, const float* __restrict__ ew,
                        char* __restrict__ ws) {
    const int* nbrCnt = (const int*)(ws + O_NBRCNT);
    const int* nbrNode= (const int*)(ws + O_NBRNODE);
    int*      mCnt   = (int*)(ws + O_MCNT);
    int*      mS     = (int*)(ws + O_MS);
    int*      mD     = (int*)(ws + O_MD);
    float*    mW     = (float*)(ws + O_MW);
    unsigned* bitmap = (unsigned*)(ws + O_BITMAP);

    __shared__ int sNode[NBR_CAP];
    __shared__ int sCnt;
    if (threadIdx.x == 0) sCnt = min(*nbrCnt, NBR_CAP);
    __syncthreads();
    int cnt = sCnt;
    for (int i = threadIdx.x; i < cnt; i += blockDim.x) sNode[i] = nbrNode[i];
    __syncthreads();
    if (blockIdx.x == 0 && threadIdx.x == 0) atomicOr(&bitmap[0], 1u);

    int i = blockIdx.x * blockDim.x + threadIdx.x;
    int e0 = i * 4;
    if (e0 >= NE) return;
    int4 s4 = *(const int4*)&ei[e0];
    int4 d4 = *(const int4*)&ei[NE + e0];
    float4 w4 = *(const float4*)&ew[e0];
    int ss[4] = {s4.x, s4.y, s4.z, s4.w};
    int dd[4] = {d4.x, d4.y, d4.z, d4.w};
    float wv[4] = {w4.x, w4.y, w4.z, w4.w};
    bool m[4];
    #pragma unroll
    for (int k = 0; k < 4; ++k) m[k] = (dd[k] == 0);
    for (int j = 0; j < cnt; ++j) {
        int nv = sNode[j];
        #pragma unroll
        for (int k = 0; k < 4; ++k) m[k] |= (dd[k] == nv);
    }
    #pragma unroll
    for (int k = 0; k < 4; ++k) {
        int s = ss[k], d = dd[k];
        float w = wv[k];
        if (s == d || w == 0.f || !m[k]) continue;
        int slot = atomicAdd(mCnt, 1);
        if (slot < M_CAP) { mS[slot] = s; mD[slot] = d; mW[slot] = w; }
        atomicOr(&bitmap[s >> 5], 1u << (s & 31));
        atomicOr(&bitmap[d >> 5], 1u << (d & 31));
    }
}

// Scan 3: deg[s] += w only for bitmap-marked srcs.
__global__ void k_deg(const int* __restrict__ ei, const float* __restrict__ ew,
                      char* __restrict__ ws) {
    const unsigned* bitmap = (const unsigned*)(ws + O_BITMAP);
    float* deg = (float*)(ws + O_DEG);
    int i = blockIdx.x * blockDim.x + threadIdx.x;
    int e0 = i * 4;
    if (e0 >= NE) return;
    int4 s4 = *(const int4*)&ei[e0];
    int4 d4 = *(const int4*)&ei[NE + e0];
    float4 w4 = *(const float4*)&ew[e0];
    int ss[4] = {s4.x, s4.y, s4.z, s4.w};
    int dd[4] = {d4.x, d4.y, d4.z, d4.w};
    float wv[4] = {w4.x, w4.y, w4.z, w4.w};
    #pragma unroll
    for (int k = 0; k < 4; ++k) {
        int s = ss[k];
        if (s == dd[k] || wv[k] == 0.f) continue;
        if (bitmap[s >> 5] & (1u << (s & 31)))
            atomicAdd(&deg[s], wv[k]);
    }
}

// Graph: 96 blocks x 256 thr. Inline coef -> 4-deep pipelined gather ->
// tslice -> gemv partials -> gpart (plain stores; kernel boundary = coherence).
__global__ __launch_bounds__(TPB) void k_graph(
    const float* __restrict__ x, const float* __restrict__ h,
    const float* __restrict__ theta_x, const float* __restrict__ theta_h,
    char* __restrict__ ws) {

    const float* deg    = (const float*)(ws + O_DEG);
    const int*   nbrCnt = (const int*)(ws + O_NBRCNT);
    const int*   mCnt   = (const int*)(ws + O_MCNT);
    const int*   nbrNode= (const int*)(ws + O_NBRNODE);
    const float* nbrW   = (const float*)(ws + O_NBRW);
    const int*   mS     = (const int*)(ws + O_MS);
    const int*   mD     = (const int*)(ws + O_MD);
    const float* mW     = (const float*)(ws + O_MW);
    float*       gpart  = (float*)(ws + O_GPART);

    __shared__ int   sNode[NBR_CAP];
    __shared__ float sWl[NBR_CAP];
    __shared__ float cf1[ECHUNK], cf2[ECHUNK];
    __shared__ int   sS[ECHUNK];
    __shared__ float tp1[GRP][PSLICE], tp2[GRP][PSLICE];
    __shared__ float tslice[PSLICE];
    __shared__ int   sCnt, sMcnt;

    const int tid = threadIdx.x, bid = blockIdx.x;
    if (tid == 0) { sCnt = min(*nbrCnt, NBR_CAP); sMcnt = min(*mCnt, M_CAP); }
    __syncthreads();
    const int ncnt = sCnt, mcnt = sMcnt;
    for (int i = tid; i < ncnt; i += TPB) { sNode[i] = nbrNode[i]; sWl[i] = nbrW[i]; }
    __syncthreads();

    const bool isx = bid < 32;                         // 384 x-rows, 768 h-rows
    const int qstart = bid * PSLICE - (isx ? 0 : 3 * FD);
    const float* fb0 = isx ? x : h;
    const int fstride = isx ? FD : HDIM;

    const int pl = tid % PSLICE, gr = tid / PSLICE;
    const float* fbase = fb0 + (qstart + pl) % fstride;
    const float dis0 = dis_of(deg[0]);

    float a1 = 0.f, a2 = 0.f;
    for (int c0i = 0; c0i < mcnt; c0i += ECHUNK) {
        int clen = min(ECHUNK, mcnt - c0i);
        for (int i = tid; i < clen; i += TPB) {        // inline per-edge coefs
            int sI = mS[c0i + i], dI = mD[c0i + i];
            float w = mW[c0i + i];
            float disd = dis_of(deg[dI]);
            float wn = dis_of(deg[sI]) * w * disd;
            float Wd = 0.f;
            for (int j = 0; j < ncnt; ++j) Wd += (sNode[j] == dI) ? sWl[j] : 0.f;
            cf1[i] = (dI == 0) ? wn : 0.f;
            cf2[i] = wn * (dis0 * disd * Wd);
            sS[i] = sI;
        }
        __syncthreads();
        if (gr < GRP) {                                // 4-deep pipelined gather
            int i = gr;
            for (; i + 3 * GRP < clen; i += 4 * GRP) {
                int s0 = sS[i], s1 = sS[i + GRP], s2 = sS[i + 2 * GRP], s3 = sS[i + 3 * GRP];
                float c10 = cf1[i], c11 = cf1[i + GRP], c12 = cf1[i + 2 * GRP], c13 = cf1[i + 3 * GRP];
                float c20 = cf2[i], c21 = cf2[i + GRP], c22 = cf2[i + 2 * GRP], c23 = cf2[i + 3 * GRP];
                float v0 = fbase[(size_t)s0 * fstride];
                float v1 = fbase[(size_t)s1 * fstride];
                float v2 = fbase[(size_t)s2 * fstride];
                float v3 = fbase[(size_t)s3 * fstride];
                a1 += c10 * v0 + c11 * v1 + c12 * v2 + c13 * v3;
                a2 += c20 * v0 + c21 * v1 + c22 * v2 + c23 * v3;
            }
            for (; i < clen; i += GRP) {
                float v = fbase[(size_t)sS[i] * fstride];
                a1 += cf1[i] * v;
                a2 += cf2[i] * v;
            }
        }
        __syncthreads();
    }
    if (gr < GRP) { tp1[gr][pl] = a1; tp2[gr][pl] = a2; }
    __syncthreads();
    if (tid < PSLICE) {
        float A1 = 0.f, A2 = 0.f;
        #pragma unroll
        for (int g2 = 0; g2 < GRP; ++g2) { A1 += tp1[g2][tid]; A2 += tp2[g2][tid]; }
        int q = qstart + tid;
        int ko = q / fstride;
        float ff0 = fb0[q % fstride];
        tslice[tid] = (ko == 0) ? ff0 : ((ko == 1) ? -A1 : 2.f * A2 - ff0);
    }
    __syncthreads();

    {   // gemv over the block's 12 p-rows; plain stores to gpart
        const float* tb = isx ? theta_x : theta_h;
        const size_t gs = isx ? (size_t)(3 * FD) * HDIM : (size_t)(3 * HDIM) * HDIM;
        float g0 = 0.f, g1 = 0.f, g2v = 0.f, g3 = 0.f;
        #pragma unroll
        for (int pp = 0; pp < PSLICE; ++pp) {
            float tv = tslice[pp];
            const float* row = tb + (size_t)(qstart + pp) * HDIM;
            g0  += tv * row[tid];
            g1  += tv * row[gs + tid];
            g2v += tv * row[2 * gs + tid];
            g3  += tv * row[3 * gs + tid];
        }
        float* gp = gpart + (size_t)bid * 1024;
        gp[tid] = g0;
        gp[HDIM + tid] = g1;
        gp[2 * HDIM + tid] = g2v;
        gp[3 * HDIM + tid] = g3;
    }
}

// Tail: 32 blocks x 256 thr. gpart reduce -> gates -> 7 steps.
// Exchange: producers publish tagged u64 via ATOMIC EXCHANGE (RMW commits at
// the LLC — no store-drain wait); each dim gets its own 32B slot (parallel
// RMWs); every thread polls its own dim's word and keeps the payload in reg.
__global__ __launch_bounds__(TPB) void k_tail2(
    const float* __restrict__ x, const float* __restrict__ c,
    const float* __restrict__ bias_x, const float* __restrict__ bias_h,
    const float* __restrict__ w_c, const float* __restrict__ b_gate,
    const float* __restrict__ w_ih, const float* __restrict__ w_hh,
    const float* __restrict__ b_ih, const float* __restrict__ b_hh,
    const float* __restrict__ w_out, const float* __restrict__ b_out,
    float* __restrict__ out, char* __restrict__ ws) {

    unsigned long long* hsync = (unsigned long long*)(ws + O_HSYNC);  // slot = (t*256+dim)*4
    const float* gpart = (const float*)(ws + O_GPART);

    __shared__ __align__(16) float sh[HDIM];
    __shared__ float sdot[32];
    __shared__ float swsum[4];

    const int tid = threadIdx.x, bid = blockIdx.x;

    // w_hh rows in VGPRs (proven no-spill layout: 32 rows/block, 8 thr/row)
    const int rl = tid >> 3, seg = tid & 7;
    const int grow = (rl >> 3) * HDIM + bid * 8 + (rl & 7);
    float4 wreg[8];
    #pragma unroll
    for (int k = 0; k < 8; ++k)
        wreg[k] = *(const float4*)&w_hh[(size_t)grow * HDIM + seg * 32 + k * 4];
    const float wih_r = w_ih[grow];
    const float br    = b_ih[grow] + b_hh[grow];
    const float bo    = b_out[0];
    const float wout_r = w_out[tid];

    // gpart reduce for this block's 32 gate-dims: d = tid>>3, 8 threads/dim
    {
        const int d = tid >> 3, j = tid & 7;
        const int g = d >> 3, kk = d & 7, o = bid * 8 + kk;
        float s = 0.f;
        #pragma unroll
        for (int pb = j; pb < GB; pb += 8) s += gpart[(size_t)pb * 1024 + g * HDIM + o];
        s += __shfl_down(s, 4);
        s += __shfl_down(s, 2);
        s += __shfl_down(s, 1);
        if (j == 0) sdot[d] = s;
    }
    __syncthreads();

    // gates -> h0 publish via RMW swap (tag 1); c0 in creg
    float creg = 0.f;
    if (tid < 8) {
        const int o = bid * 8 + tid;
        float g0 = sdot[tid]      + bias_x[o]            + bias_h[o];
        float g1 = sdot[8 + tid]  + bias_x[HDIM + o]     + bias_h[HDIM + o];
        float g2 = sdot[16 + tid] + bias_x[2 * HDIM + o] + bias_h[2 * HDIM + o];
        float g3 = sdot[24 + tid] + bias_x[3 * HDIM + o] + bias_h[3 * HDIM + o];
        float c0 = c[o];
        float I  = sigm(g0 + w_c[o] * c0 + b_gate[o]);
        float Fg = sigm(g1 + w_c[HDIM + o] * c0 + b_gate[HDIM + o]);
        float Cn = Fg * c0 + I * tanhf(g2 + b_gate[2 * HDIM + o]);
        float O  = sigm(g3 + w_c[2 * HDIM + o] * Cn + b_gate[3 * HDIM + o]);
        float h0 = O * tanhf(Cn);
        creg = Cn;
        unsigned long long pk = (1ull << 32) | (unsigned long long)__float_as_uint(h0);
        (void)__hip_atomic_exchange(&hsync[(size_t)o * 4], pk,
                                    __ATOMIC_RELEASE, __HIP_MEMORY_SCOPE_SYSTEM);
    }
    // parallel poll: every thread its own h0 slot (busy-spin)
    {
        unsigned long long v;
        int sp = 0;
        do {
            v = __hip_atomic_load(&hsync[(size_t)tid * 4],
                                  __ATOMIC_RELAXED, __HIP_MEMORY_SCOPE_SYSTEM);
            if ((unsigned)(v >> 32) == 1u) break;
        } while (++sp < SPIN_CAP);
        sh[tid] = __uint_as_float((unsigned)v);
    }
    __syncthreads();
    float sinp = x[FD - 1];

    for (int t = 0; t < TT; ++t) {
        // dot on sh = h(t)
        float acc = 0.f;
        const float* shh = &sh[seg * 32];
        #pragma unroll
        for (int k = 0; k < 8; ++k) {
            float4 hv = *(const float4*)&shh[k * 4];
            acc += hv.x * wreg[k].x + hv.y * wreg[k].y + hv.z * wreg[k].z + hv.w * wreg[k].w;
        }
        acc += __shfl_down(acc, 4);
        acc += __shfl_down(acc, 2);
        acc += __shfl_down(acc, 1);
        if (seg == 0) sdot[rl] = acc + sinp * wih_r + br;
        __syncthreads();                        // S1: sh reads done, sdot ready
        if (tid < 8) {
            float iv = sdot[tid], fv = sdot[8 + tid], gv = sdot[16 + tid], ov = sdot[24 + tid];
            float cn = sigm(fv) * creg + sigm(iv) * tanhf(gv);
            float hn = sigm(ov) * tanhf(cn);
            creg = cn;
            unsigned long long pk = (((unsigned long long)(t + 2)) << 32)
                                  | (unsigned long long)__float_as_uint(hn);
            (void)__hip_atomic_exchange(&hsync[(size_t)((t + 1) * HDIM + bid * 8 + tid) * 4],
                                        pk, __ATOMIC_RELEASE, __HIP_MEMORY_SCOPE_SYSTEM);
        }
        // parallel poll: every thread its own h(t+1) slot; payload stays in reg
        float hval;
        {
            unsigned long long v;
            int sp = 0;
            do {
                v = __hip_atomic_load(&hsync[(size_t)((t + 1) * HDIM + tid) * 4],
                                      __ATOMIC_RELAXED, __HIP_MEMORY_SCOPE_SYSTEM);
                if ((unsigned)(v >> 32) == (unsigned)(t + 2)) break;
            } while (++sp < SPIN_CAP);
            hval = __uint_as_float((unsigned)v);
        }
        sh[tid] = hval;
        float pw = wout_r * hval;               // register payload, no LDS wait
        pw += __shfl_down(pw, 32);
        pw += __shfl_down(pw, 16);
        pw += __shfl_down(pw, 8);
        pw += __shfl_down(pw, 4);
        pw += __shfl_down(pw, 2);
        pw += __shfl_down(pw, 1);
        if ((tid & 63) == 0) swsum[tid >> 6] = pw;
        __syncthreads();                        // S2: swsum + new sh visible
        float sval = swsum[0] + swsum[1] + swsum[2] + swsum[3] + bo;
        sinp = sval;                            // input to step t+1
        if (bid == 0 && tid == 0) out[t] = sval;
    }
}

extern "C" void kernel_launch(void* const* d_in, const int* in_sizes, int n_in,
                              void* d_out, int out_size, void* d_ws, size_t ws_size,
                              hipStream_t stream) {
    const float* x       = (const float*)d_in[0];
    const int*   ei      = (const int*)d_in[1];
    const float* ew      = (const float*)d_in[2];
    const float* h       = (const float*)d_in[3];
    const float* c       = (const float*)d_in[4];
    const float* theta_x = (const float*)d_in[5];
    const float* bias_x  = (const float*)d_in[6];
    const float* theta_h = (const float*)d_in[7];
    const float* bias_h  = (const float*)d_in[8];
    const float* w_c     = (const float*)d_in[9];
    const float* b_gate  = (const float*)d_in[10];
    const float* w_ih    = (const float*)d_in[11];
    const float* w_hh    = (const float*)d_in[12];
    const float* b_ih    = (const float*)d_in[13];
    const float* b_hh    = (const float*)d_in[14];
    const float* w_out   = (const float*)d_in[15];
    const float* b_out   = (const float*)d_in[16];
    char* ws = (char*)d_ws;
    float* out = (float*)d_out;

    hipMemsetAsync(ws, 0, 64, stream);          // nbrCnt; rest zeroed by k_nbr

    int eb4 = (NE / 4 + TPB - 1) / TPB;         // 782 blocks
    k_nbr<<<eb4, TPB, 0, stream>>>(ei, ew, ws);
    k_match<<<eb4, TPB, 0, stream>>>(ei, ew, ws);
    k_deg<<<eb4, TPB, 0, stream>>>(ei, ew, ws);
    k_graph<<<GB, TPB, 0, stream>>>(x, h, theta_x, theta_h, ws);
    k_tail2<<<SB, TPB, 0, stream>>>(x, c, bias_x, bias_h, w_c, b_gate,
                                    w_ih, w_hh, b_ih, b_hh, w_out, b_out, out, ws);
}

// Round 19
// 55.304 us; speedup vs baseline: 1.2047x; 1.0147x over previous
//
#include <hip/hip_runtime.h>
#include <math.h>

#define NN 50000
#define FD 128
#define HDIM 256
#define NE 800000
#define NBR_CAP 512
#define M_CAP 8192
#define TT 7
#define TPB 256
#define GB 96              // k_graph blocks: 96 x 12 = 1152 p-values
#define PSLICE 12
#define GRP 21             // gather groups per block (252 threads used)
#define ECHUNK 2048
#define SB 32              // k_tail2 blocks
#define SPIN_CAP 50000000

// ws offsets
#define O_NBRCNT   0       // zeroed by 64-B memset node
#define O_MCNT     64
#define O_HSYNC    128     // (TT+1)*256 dims x 64B line = 131072 -> 131200
#define O_DEG      131200  // NN f -> 331200
#define O_BITMAP   331200  // 1568 u32 -> 337472
#define O_ZERO_END 337472  // k_nbr zeroes [O_MCNT, O_ZERO_END)
#define O_NBRNODE  337472  // NBR_CAP i
#define O_NBRW     339520  // NBR_CAP f
#define O_MS       341568  // M_CAP i
#define O_MD       374336  // M_CAP i
#define O_MW       407104  // M_CAP f -> 439872
#define O_GPART    439872  // GB*1024 f -> 833088 (fully overwritten, no zero)

__device__ __forceinline__ float sigm(float v) { return 1.f / (1.f + expf(-v)); }
__device__ __forceinline__ float dis_of(float dg) {
    return dg > 0.f ? rsqrtf(fmaxf(dg, 1e-20f)) : 0.f;
}

// Scan 1: zero ctrl/hsync/deg/bitmap; collect nbr(0).
__global__ void k_nbr(const int* __restrict__ ei, const float* __restrict__ ew,
                      char* __restrict__ ws) {
    int*   nbrCnt = (int*)(ws + O_NBRCNT);
    int*   nbrNode= (int*)(ws + O_NBRNODE);
    float* nbrW   = (float*)(ws + O_NBRW);

    int gid = blockIdx.x * blockDim.x + threadIdx.x;
    if (gid < (O_ZERO_END - O_MCNT) / 4) ((unsigned*)(ws + O_MCNT))[gid] = 0u;

    int e0 = gid * 4;
    if (e0 >= NE) return;
    int4 d4 = *(const int4*)&ei[NE + e0];
    float4 w4 = *(const float4*)&ew[e0];
    int dd[4] = {d4.x, d4.y, d4.z, d4.w};
    float wv[4] = {w4.x, w4.y, w4.z, w4.w};
    #pragma unroll
    for (int k = 0; k < 4; ++k) {
        if (dd[k] == 0 && wv[k] != 0.f) {
            int s = ei[e0 + k];
            if (s != 0) {
                int slot = atomicAdd(nbrCnt, 1);
                if (slot < NBR_CAP) { nbrNode[slot] = s; nbrW[slot] = wv[k]; }
            }
        }
    }
}

// Scan 2: match edges with d==0 or d in nbr(0); record (s,d,w); mark needed nodes.
__global__ void k_match(const int* __restrict__ ei, const float* __restrict__ ew,
                        char* __restrict__ ws) {
    const int* nbrCnt = (const int*)(ws + O_NBRCNT);
    const int* nbrNode= (const int*)(ws + O_NBRNODE);
    int*      mCnt   = (int*)(ws + O_MCNT);
    int*      mS     = (int*)(ws + O_MS);
    int*      mD     = (int*)(ws + O_MD);
    float*    mW     = (float*)(ws + O_MW);
    unsigned* bitmap = (unsigned*)(ws + O_BITMAP);

    __shared__ int sNode[NBR_CAP];
    __shared__ int sCnt;
    if (threadIdx.x == 0) sCnt = min(*nbrCnt, NBR_CAP);
    __syncthreads();
    int cnt = sCnt;
    for (int i = threadIdx.x; i < cnt; i += blockDim.x) sNode[i] = nbrNode[i];
    __syncthreads();
    if (blockIdx.x == 0 && threadIdx.x == 0) atomicOr(&bitmap[0], 1u);

    int i = blockIdx.x * blockDim.x + threadIdx.x;
    int e0 = i * 4;
    if (e0 >= NE) return;
    int4 s4 = *(const int4*)&ei[e0];
    int4 d4 = *(const int4*)&ei[NE + e0];
    float4 w4 = *(const float4*)&ew[e0];
    int ss[4] = {s4.x, s4.y, s4.z, s4.w};
    int dd[4] = {d4.x, d4.y, d4.z, d4.w};
    float wv[4] = {w4.x, w4.y, w4.z, w4.w};
    bool m[4];
    #pragma unroll
    for (int k = 0; k < 4; ++k) m[k] = (dd[k] == 0);
    for (int j = 0; j < cnt; ++j) {
        int nv = sNode[j];
        #pragma unroll
        for (int k = 0; k < 4; ++k) m[k] |= (dd[k] == nv);
    }
    #pragma unroll
    for (int k = 0; k < 4; ++k) {
        int s = ss[k], d = dd[k];
        float w = wv[k];
        if (s == d || w == 0.f || !m[k]) continue;
        int slot = atomicAdd(mCnt, 1);
        if (slot < M_CAP) { mS[slot] = s; mD[slot] = d; mW[slot] = w; }
        atomicOr(&bitmap[s >> 5], 1u << (s & 31));
        atomicOr(&bitmap[d >> 5], 1u << (d & 31));
    }
}

// Scan 3: deg[s] += w only for bitmap-marked srcs.
__global__ void k_deg(const int* __restrict__ ei, const float* __restrict__ ew,
                      char* __restrict__ ws) {
    const unsigned* bitmap = (const unsigned*)(ws + O_BITMAP);
    float* deg = (float*)(ws + O_DEG);
    int i = blockIdx.x * blockDim.x + threadIdx.x;
    int e0 = i * 4;
    if (e0 >= NE) return;
    int4 s4 = *(const int4*)&ei[e0];
    int4 d4 = *(const int4*)&ei[NE + e0];
    float4 w4 = *(const float4*)&ew[e0];
    int ss[4] = {s4.x, s4.y, s4.z, s4.w};
    int dd[4] = {d4.x, d4.y, d4.z, d4.w};
    float wv[4] = {w4.x, w4.y, w4.z, w4.w};
    #pragma unroll
    for (int k = 0; k < 4; ++k) {
        int s = ss[k];
        if (s == dd[k] || wv[k] == 0.f) continue;
        if (bitmap[s >> 5] & (1u << (s & 31)))
            atomicAdd(&deg[s], wv[k]);
    }
}

// Graph: 96 blocks x 256 thr. Inline coef -> 4-deep pipelined gather ->
// tslice -> gemv partials -> gpart (plain stores; kernel boundary = coherence).
__global__ __launch_bounds__(TPB) void k_graph(
    const float* __restrict__ x, const float* __restrict__ h,
    const float* __restrict__ theta_x, const float* __restrict__ theta_h,
    char* __restrict__ ws) {

    const float* deg    = (const float*)(ws + O_DEG);
    const int*   nbrCnt = (const int*)(ws + O_NBRCNT);
    const int*   mCnt   = (const int*)(ws + O_MCNT);
    const int*   nbrNode= (const int*)(ws + O_NBRNODE);
    const float* nbrW   = (const float*)(ws + O_NBRW);
    const int*   mS     = (const int*)(ws + O_MS);
    const int*   mD     = (const int*)(ws + O_MD);
    const float* mW     = (const float*)(ws + O_MW);
    float*       gpart  = (float*)(ws + O_GPART);

    __shared__ int   sNode[NBR_CAP];
    __shared__ float sWl[NBR_CAP];
    __shared__ float cf1[ECHUNK], cf2[ECHUNK];
    __shared__ int   sS[ECHUNK];
    __shared__ float tp1[GRP][PSLICE], tp2[GRP][PSLICE];
    __shared__ float tslice[PSLICE];
    __shared__ int   sCnt, sMcnt;

    const int tid = threadIdx.x, bid = blockIdx.x;
    if (tid == 0) { sCnt = min(*nbrCnt, NBR_CAP); sMcnt = min(*mCnt, M_CAP); }
    __syncthreads();
    const int ncnt = sCnt, mcnt = sMcnt;
    for (int i = tid; i < ncnt; i += TPB) { sNode[i] = nbrNode[i]; sWl[i] = nbrW[i]; }
    __syncthreads();

    const bool isx = bid < 32;                         // 384 x-rows, 768 h-rows
    const int qstart = bid * PSLICE - (isx ? 0 : 3 * FD);
    const float* fb0 = isx ? x : h;
    const int fstride = isx ? FD : HDIM;

    const int pl = tid % PSLICE, gr = tid / PSLICE;
    const float* fbase = fb0 + (qstart + pl) % fstride;
    const float dis0 = dis_of(deg[0]);

    float a1 = 0.f, a2 = 0.f;
    for (int c0i = 0; c0i < mcnt; c0i += ECHUNK) {
        int clen = min(ECHUNK, mcnt - c0i);
        for (int i = tid; i < clen; i += TPB) {        // inline per-edge coefs
            int sI = mS[c0i + i], dI = mD[c0i + i];
            float w = mW[c0i + i];
            float disd = dis_of(deg[dI]);
            float wn = dis_of(deg[sI]) * w * disd;
            float Wd = 0.f;
            for (int j = 0; j < ncnt; ++j) Wd += (sNode[j] == dI) ? sWl[j] : 0.f;
            cf1[i] = (dI == 0) ? wn : 0.f;
            cf2[i] = wn * (dis0 * disd * Wd);
            sS[i] = sI;
        }
        __syncthreads();
        if (gr < GRP) {                                // 4-deep pipelined gather
            int i = gr;
            for (; i + 3 * GRP < clen; i += 4 * GRP) {
                int s0 = sS[i], s1 = sS[i + GRP], s2 = sS[i + 2 * GRP], s3 = sS[i + 3 * GRP];
                float c10 = cf1[i], c11 = cf1[i + GRP], c12 = cf1[i + 2 * GRP], c13 = cf1[i + 3 * GRP];
                float c20 = cf2[i], c21 = cf2[i + GRP], c22 = cf2[i + 2 * GRP], c23 = cf2[i + 3 * GRP];
                float v0 = fbase[(size_t)s0 * fstride];
                float v1 = fbase[(size_t)s1 * fstride];
                float v2 = fbase[(size_t)s2 * fstride];
                float v3 = fbase[(size_t)s3 * fstride];
                a1 += c10 * v0 + c11 * v1 + c12 * v2 + c13 * v3;
                a2 += c20 * v0 + c21 * v1 + c22 * v2 + c23 * v3;
            }
            for (; i < clen; i += GRP) {
                float v = fbase[(size_t)sS[i] * fstride];
                a1 += cf1[i] * v;
                a2 += cf2[i] * v;
            }
        }
        __syncthreads();
    }
    if (gr < GRP) { tp1[gr][pl] = a1; tp2[gr][pl] = a2; }
    __syncthreads();
    if (tid < PSLICE) {
        float A1 = 0.f, A2 = 0.f;
        #pragma unroll
        for (int g2 = 0; g2 < GRP; ++g2) { A1 += tp1[g2][tid]; A2 += tp2[g2][tid]; }
        int q = qstart + tid;
        int ko = q / fstride;
        float ff0 = fb0[q % fstride];
        tslice[tid] = (ko == 0) ? ff0 : ((ko == 1) ? -A1 : 2.f * A2 - ff0);
    }
    __syncthreads();

    {   // gemv over the block's 12 p-rows; plain stores to gpart
        const float* tb = isx ? theta_x : theta_h;
        const size_t gs = isx ? (size_t)(3 * FD) * HDIM : (size_t)(3 * HDIM) * HDIM;
        float g0 = 0.f, g1 = 0.f, g2v = 0.f, g3 = 0.f;
        #pragma unroll
        for (int pp = 0; pp < PSLICE; ++pp) {
            float tv = tslice[pp];
            const float* row = tb + (size_t)(qstart + pp) * HDIM;
            g0  += tv * row[tid];
            g1  += tv * row[gs + tid];
            g2v += tv * row[2 * gs + tid];
            g3  += tv * row[3 * gs + tid];
        }
        float* gp = gpart + (size_t)bid * 1024;
        gp[tid] = g0;
        gp[HDIM + tid] = g1;
        gp[2 * HDIM + tid] = g2v;
        gp[3 * HDIM + tid] = g3;
    }
}

// Tail: 32 blocks x 256 thr. gpart reduce -> gates -> 7 steps.
// Exchange (r14 mechanism, line-padded): producers relaxed-store tagged u64,
// ONE PER 64B LINE; every thread polls its own private line (zero line sharing).
__global__ __launch_bounds__(TPB) void k_tail2(
    const float* __restrict__ x, const float* __restrict__ c,
    const float* __restrict__ bias_x, const float* __restrict__ bias_h,
    const float* __restrict__ w_c, const float* __restrict__ b_gate,
    const float* __restrict__ w_ih, const float* __restrict__ w_hh,
    const float* __restrict__ b_ih, const float* __restrict__ b_hh,
    const float* __restrict__ w_out, const float* __restrict__ b_out,
    float* __restrict__ out, char* __restrict__ ws) {

    unsigned long long* hsync = (unsigned long long*)(ws + O_HSYNC);  // slot = (t*256+dim)*8
    const float* gpart = (const float*)(ws + O_GPART);

    __shared__ __align__(16) float sh[HDIM];
    __shared__ float sdot[32];
    __shared__ float swsum[4];

    const int tid = threadIdx.x, bid = blockIdx.x;

    // w_hh rows in VGPRs (proven no-spill layout: 32 rows/block, 8 thr/row)
    const int rl = tid >> 3, seg = tid & 7;
    const int grow = (rl >> 3) * HDIM + bid * 8 + (rl & 7);
    float4 wreg[8];
    #pragma unroll
    for (int k = 0; k < 8; ++k)
        wreg[k] = *(const float4*)&w_hh[(size_t)grow * HDIM + seg * 32 + k * 4];
    const float wih_r = w_ih[grow];
    const float br    = b_ih[grow] + b_hh[grow];
    const float bo    = b_out[0];
    const float wout_r = w_out[tid];

    // gpart reduce for this block's 32 gate-dims: d = tid>>3, 8 threads/dim
    {
        const int d = tid >> 3, j = tid & 7;
        const int g = d >> 3, kk = d & 7, o = bid * 8 + kk;
        float s = 0.f;
        #pragma unroll
        for (int pb = j; pb < GB; pb += 8) s += gpart[(size_t)pb * 1024 + g * HDIM + o];
        s += __shfl_down(s, 4);
        s += __shfl_down(s, 2);
        s += __shfl_down(s, 1);
        if (j == 0) sdot[d] = s;
    }
    __syncthreads();

    // gates -> h0 publish (tag 1, relaxed store to private line); c0 in creg
    float creg = 0.f;
    if (tid < 8) {
        const int o = bid * 8 + tid;
        float g0 = sdot[tid]      + bias_x[o]            + bias_h[o];
        float g1 = sdot[8 + tid]  + bias_x[HDIM + o]     + bias_h[HDIM + o];
        float g2 = sdot[16 + tid] + bias_x[2 * HDIM + o] + bias_h[2 * HDIM + o];
        float g3 = sdot[24 + tid] + bias_x[3 * HDIM + o] + bias_h[3 * HDIM + o];
        float c0 = c[o];
        float I  = sigm(g0 + w_c[o] * c0 + b_gate[o]);
        float Fg = sigm(g1 + w_c[HDIM + o] * c0 + b_gate[HDIM + o]);
        float Cn = Fg * c0 + I * tanhf(g2 + b_gate[2 * HDIM + o]);
        float O  = sigm(g3 + w_c[2 * HDIM + o] * Cn + b_gate[3 * HDIM + o]);
        float h0 = O * tanhf(Cn);
        creg = Cn;
        unsigned long long pk = (1ull << 32) | (unsigned long long)__float_as_uint(h0);
        __hip_atomic_store(&hsync[(size_t)o * 8], pk,
                           __ATOMIC_RELAXED, __HIP_MEMORY_SCOPE_SYSTEM);
    }
    // parallel poll: every thread its own private line
    {
        unsigned long long v;
        int sp = 0;
        do {
            v = __hip_atomic_load(&hsync[(size_t)tid * 8],
                                  __ATOMIC_RELAXED, __HIP_MEMORY_SCOPE_SYSTEM);
            if ((unsigned)(v >> 32) == 1u) break;
        } while (++sp < SPIN_CAP);
        sh[tid] = __uint_as_float((unsigned)v);
    }
    __syncthreads();
    float sinp = x[FD - 1];

    for (int t = 0; t < TT; ++t) {
        // dot on sh = h(t)
        float acc = 0.f;
        const float* shh = &sh[seg * 32];
        #pragma unroll
        for (int k = 0; k < 8; ++k) {
            float4 hv = *(const float4*)&shh[k * 4];
            acc += hv.x * wreg[k].x + hv.y * wreg[k].y + hv.z * wreg[k].z + hv.w * wreg[k].w;
        }
        acc += __shfl_down(acc, 4);
        acc += __shfl_down(acc, 2);
        acc += __shfl_down(acc, 1);
        if (seg == 0) sdot[rl] = acc + sinp * wih_r + br;
        __syncthreads();                        // S1: sh reads done, sdot ready
        if (tid < 8) {
            float iv = sdot[tid], fv = sdot[8 + tid], gv = sdot[16 + tid], ov = sdot[24 + tid];
            float cn = sigm(fv) * creg + sigm(iv) * tanhf(gv);
            float hn = sigm(ov) * tanhf(cn);
            creg = cn;
            unsigned long long pk = (((unsigned long long)(t + 2)) << 32)
                                  | (unsigned long long)__float_as_uint(hn);
            __hip_atomic_store(&hsync[(size_t)((t + 1) * HDIM + bid * 8 + tid) * 8], pk,
                               __ATOMIC_RELAXED, __HIP_MEMORY_SCOPE_SYSTEM);
        }
        // parallel poll: every thread its own private line; payload stays in reg
        float hval;
        {
            unsigned long long v;
            int sp = 0;
            do {
                v = __hip_atomic_load(&hsync[(size_t)((t + 1) * HDIM + tid) * 8],
                                      __ATOMIC_RELAXED, __HIP_MEMORY_SCOPE_SYSTEM);
                if ((unsigned)(v >> 32) == (unsigned)(t + 2)) break;
            } while (++sp < SPIN_CAP);
            hval = __uint_as_float((unsigned)v);
        }
        sh[tid] = hval;
        float pw = wout_r * hval;               // register payload, no LDS wait
        pw += __shfl_down(pw, 32);
        pw += __shfl_down(pw, 16);
        pw += __shfl_down(pw, 8);
        pw += __shfl_down(pw, 4);
        pw += __shfl_down(pw, 2);
        pw += __shfl_down(pw, 1);
        if ((tid & 63) == 0) swsum[tid >> 6] = pw;
        __syncthreads();                        // S2: swsum + new sh visible
        float sval = swsum[0] + swsum[1] + swsum[2] + swsum[3] + bo;
        sinp = sval;                            // input to step t+1
        if (bid == 0 && tid == 0) out[t] = sval;
    }
}

extern "C" void kernel_launch(void* const* d_in, const int* in_sizes, int n_in,
                              void* d_out, int out_size, void* d_ws, size_t ws_size,
                              hipStream_t stream) {
    const float* x       = (const float*)d_in[0];
    const int*   ei      = (const int*)d_in[1];
    const float* ew      = (const float*)d_in[2];
    const float* h       = (const float*)d_in[3];
    const float* c       = (const float*)d_in[4];
    const float* theta_x = (const float*)d_in[5];
    const float* bias_x  = (const float*)d_in[6];
    const float* theta_h = (const float*)d_in[7];
    const float* bias_h  = (const float*)d_in[8];
    const float* w_c     = (const float*)d_in[9];
    const float* b_gate  = (const float*)d_in[10];
    const float* w_ih    = (const float*)d_in[11];
    const float* w_hh    = (const float*)d_in[12];
    const float* b_ih    = (const float*)d_in[13];
    const float* b_hh    = (const float*)d_in[14];
    const float* w_out   = (const float*)d_in[15];
    const float* b_out   = (const float*)d_in[16];
    char* ws = (char*)d_ws;
    float* out = (float*)d_out;

    hipMemsetAsync(ws, 0, 64, stream);          // nbrCnt; rest zeroed by k_nbr

    int eb4 = (NE / 4 + TPB - 1) / TPB;         // 782 blocks
    k_nbr<<<eb4, TPB, 0, stream>>>(ei, ew, ws);
    k_match<<<eb4, TPB, 0, stream>>>(ei, ew, ws);
    k_deg<<<eb4, TPB, 0, stream>>>(ei, ew, ws);
    k_graph<<<GB, TPB, 0, stream>>>(x, h, theta_x, theta_h, ws);
    k_tail2<<<SB, TPB, 0, stream>>>(x, c, bias_x, bias_h, w_c, b_gate,
                                    w_ih, w_hh, b_ih, b_hh, w_out, b_out, out, ws);
}

// Round 20
// 54.840 us; speedup vs baseline: 1.2149x; 1.0085x over previous
//
#include <hip/hip_runtime.h>
#include <math.h>

#define NN 50000
#define FD 128
#define HDIM 256
#define NE 800000
#define NBR_CAP 512
#define M_CAP 8192
#define TT 7
#define TPB 256
#define GB 96              // graph blocks: 96 x 12 = 1152 p-values
#define PSLICE 12
#define GRP 21             // gather groups per block (252 threads used)
#define ECHUNK 2048
#define SBLK 32            // gates blocks in k_fused (bid 96..127)
#define FGRID (GB + SBLK)
#define SB 32              // k_tail2 blocks
#define SPIN_CAP 50000000

// ws offsets
#define O_NBRCNT   0       // zeroed by 64-B memset node
#define O_MCNT     64
#define O_GDONE    128     // GB u32 -> 512
#define O_HSYNC    512     // (TT+1)*HDIM u64 = 16384 -> 16896 (contiguous: r14-best)
#define O_HBUF     16896   // HDIM f -> 17920
#define O_CBUF     17920   // HDIM f -> 18944
#define O_DEG      18944   // NN f -> 218944
#define O_BITMAP   218944  // 1568 u32 -> 225216
#define O_ZERO_END 225216  // k_nbr zeroes [O_MCNT, O_ZERO_END)
#define O_NBRNODE  225216  // NBR_CAP i
#define O_NBRW     227264  // NBR_CAP f
#define O_MS       229312  // M_CAP i
#define O_MD       262080  // M_CAP i
#define O_MW       294848  // M_CAP f -> 327616
#define O_GPART    327616  // GB*1024 f -> 720832 (fully overwritten, no zero)

__device__ __forceinline__ float sigm(float v) { return 1.f / (1.f + expf(-v)); }
__device__ __forceinline__ float dis_of(float dg) {
    return dg > 0.f ? rsqrtf(fmaxf(dg, 1e-20f)) : 0.f;
}
__device__ __forceinline__ void ssf(float* p, float v) {
    __hip_atomic_store(p, v, __ATOMIC_RELAXED, __HIP_MEMORY_SCOPE_SYSTEM);
}
__device__ __forceinline__ float slf(const float* p) {
    return __hip_atomic_load(p, __ATOMIC_RELAXED, __HIP_MEMORY_SCOPE_SYSTEM);
}

// Scan 1: zero ctrl/gdone/hsync/hbuf/cbuf/deg/bitmap; collect nbr(0).
__global__ void k_nbr(const int* __restrict__ ei, const float* __restrict__ ew,
                      char* __restrict__ ws) {
    int*   nbrCnt = (int*)(ws + O_NBRCNT);
    int*   nbrNode= (int*)(ws + O_NBRNODE);
    float* nbrW   = (float*)(ws + O_NBRW);

    int gid = blockIdx.x * blockDim.x + threadIdx.x;
    if (gid < (O_ZERO_END - O_MCNT) / 4) ((unsigned*)(ws + O_MCNT))[gid] = 0u;

    int e0 = gid * 4;
    if (e0 >= NE) return;
    int4 d4 = *(const int4*)&ei[NE + e0];
    float4 w4 = *(const float4*)&ew[e0];
    int dd[4] = {d4.x, d4.y, d4.z, d4.w};
    float wv[4] = {w4.x, w4.y, w4.z, w4.w};
    #pragma unroll
    for (int k = 0; k < 4; ++k) {
        if (dd[k] == 0 && wv[k] != 0.f) {
            int s = ei[e0 + k];
            if (s != 0) {
                int slot = atomicAdd(nbrCnt, 1);
                if (slot < NBR_CAP) { nbrNode[slot] = s; nbrW[slot] = wv[k]; }
            }
        }
    }
}

// Scan 2: match edges with d==0 or d in nbr(0); record (s,d,w); mark needed nodes.
__global__ void k_match(const int* __restrict__ ei, const float* __restrict__ ew,
                        char* __restrict__ ws) {
    const int* nbrCnt = (const int*)(ws + O_NBRCNT);
    const int* nbrNode= (const int*)(ws + O_NBRNODE);
    int*      mCnt   = (int*)(ws + O_MCNT);
    int*      mS     = (int*)(ws + O_MS);
    int*      mD     = (int*)(ws + O_MD);
    float*    mW     = (float*)(ws + O_MW);
    unsigned* bitmap = (unsigned*)(ws + O_BITMAP);

    __shared__ int sNode[NBR_CAP];
    __shared__ int sCnt;
    if (threadIdx.x == 0) sCnt = min(*nbrCnt, NBR_CAP);
    __syncthreads();
    int cnt = sCnt;
    for (int i = threadIdx.x; i < cnt; i += blockDim.x) sNode[i] = nbrNode[i];
    __syncthreads();
    if (blockIdx.x == 0 && threadIdx.x == 0) atomicOr(&bitmap[0], 1u);

    int i = blockIdx.x * blockDim.x + threadIdx.x;
    int e0 = i * 4;
    if (e0 >= NE) return;
    int4 s4 = *(const int4*)&ei[e0];
    int4 d4 = *(const int4*)&ei[NE + e0];
    float4 w4 = *(const float4*)&ew[e0];
    int ss[4] = {s4.x, s4.y, s4.z, s4.w};
    int dd[4] = {d4.x, d4.y, d4.z, d4.w};
    float wv[4] = {w4.x, w4.y, w4.z, w4.w};
    bool m[4];
    #pragma unroll
    for (int k = 0; k < 4; ++k) m[k] = (dd[k] == 0);
    for (int j = 0; j < cnt; ++j) {
        int nv = sNode[j];
        #pragma unroll
        for (int k = 0; k < 4; ++k) m[k] |= (dd[k] == nv);
    }
    #pragma unroll
    for (int k = 0; k < 4; ++k) {
        int s = ss[k], d = dd[k];
        float w = wv[k];
        if (s == d || w == 0.f || !m[k]) continue;
        int slot = atomicAdd(mCnt, 1);
        if (slot < M_CAP) { mS[slot] = s; mD[slot] = d; mW[slot] = w; }
        atomicOr(&bitmap[s >> 5], 1u << (s & 31));
        atomicOr(&bitmap[d >> 5], 1u << (d & 31));
    }
}

// Scan 3: deg[s] += w only for bitmap-marked srcs.
__global__ void k_deg(const int* __restrict__ ei, const float* __restrict__ ew,
                      char* __restrict__ ws) {
    const unsigned* bitmap = (const unsigned*)(ws + O_BITMAP);
    float* deg = (float*)(ws + O_DEG);
    int i = blockIdx.x * blockDim.x + threadIdx.x;
    int e0 = i * 4;
    if (e0 >= NE) return;
    int4 s4 = *(const int4*)&ei[e0];
    int4 d4 = *(const int4*)&ei[NE + e0];
    float4 w4 = *(const float4*)&ew[e0];
    int ss[4] = {s4.x, s4.y, s4.z, s4.w};
    int dd[4] = {d4.x, d4.y, d4.z, d4.w};
    float wv[4] = {w4.x, w4.y, w4.z, w4.w};
    #pragma unroll
    for (int k = 0; k < 4; ++k) {
        int s = ss[k];
        if (s == dd[k] || wv[k] == 0.f) continue;
        if (bitmap[s >> 5] & (1u << (s & 31)))
            atomicAdd(&deg[s], wv[k]);
    }
}

// Fused graph + gates. 128 blocks x 256 thr.
// Blocks 0..95: graph slice -> gpart (system stores) -> release gdone[bid].
// Blocks 96..127: poll gdone (overlapped with graph); gpart reduce -> gates ->
//                 plain-store h0/c0 to hbuf/cbuf. Kernel boundary = h0 broadcast.
__global__ __launch_bounds__(TPB) void k_fused(
    const float* __restrict__ x, const float* __restrict__ h, const float* __restrict__ c,
    const float* __restrict__ theta_x, const float* __restrict__ bias_x,
    const float* __restrict__ theta_h, const float* __restrict__ bias_h,
    const float* __restrict__ w_c, const float* __restrict__ b_gate,
    char* __restrict__ ws) {

    const float*  deg    = (const float*)(ws + O_DEG);
    const int*    nbrCnt = (const int*)(ws + O_NBRCNT);
    const int*    mCnt   = (const int*)(ws + O_MCNT);
    const int*    nbrNode= (const int*)(ws + O_NBRNODE);
    const float*  nbrW   = (const float*)(ws + O_NBRW);
    const int*    mS     = (const int*)(ws + O_MS);
    const int*    mD     = (const int*)(ws + O_MD);
    const float*  mW     = (const float*)(ws + O_MW);
    float*        gpart  = (float*)(ws + O_GPART);
    unsigned*     gdone  = (unsigned*)(ws + O_GDONE);
    float*        hbuf   = (float*)(ws + O_HBUF);
    float*        cbuf   = (float*)(ws + O_CBUF);

    __shared__ int   sNode[NBR_CAP];
    __shared__ float sWl[NBR_CAP];
    __shared__ float cf1[ECHUNK], cf2[ECHUNK];
    __shared__ int   sS[ECHUNK];
    __shared__ float tp1[GRP][PSLICE], tp2[GRP][PSLICE];
    __shared__ float tslice[PSLICE];
    __shared__ float sdot[32];
    __shared__ int   sCnt, sMcnt;

    const int tid = threadIdx.x, bid = blockIdx.x;

    if (bid < GB) {
        // ================== graph block ==================
        if (tid == 0) { sCnt = min(*nbrCnt, NBR_CAP); sMcnt = min(*mCnt, M_CAP); }
        __syncthreads();
        const int ncnt = sCnt, mcnt = sMcnt;
        for (int i = tid; i < ncnt; i += TPB) { sNode[i] = nbrNode[i]; sWl[i] = nbrW[i]; }
        __syncthreads();

        const bool isx = bid < 32;                     // 384 x-rows, 768 h-rows
        const int qstart = bid * PSLICE - (isx ? 0 : 3 * FD);
        const float* fb0 = isx ? x : h;
        const int fstride = isx ? FD : HDIM;

        const int pl = tid % PSLICE, gr = tid / PSLICE;
        const float* fbase = fb0 + (qstart + pl) % fstride;
        const float dis0 = dis_of(deg[0]);

        float a1 = 0.f, a2 = 0.f;
        for (int c0i = 0; c0i < mcnt; c0i += ECHUNK) {
            int clen = min(ECHUNK, mcnt - c0i);
            for (int i = tid; i < clen; i += TPB) {    // inline per-edge coefs
                int sI = mS[c0i + i], dI = mD[c0i + i];
                float w = mW[c0i + i];
                float disd = dis_of(deg[dI]);
                float wn = dis_of(deg[sI]) * w * disd;
                float Wd = 0.f;
                for (int j = 0; j < ncnt; ++j) Wd += (sNode[j] == dI) ? sWl[j] : 0.f;
                cf1[i] = (dI == 0) ? wn : 0.f;
                cf2[i] = wn * (dis0 * disd * Wd);
                sS[i] = sI;
            }
            __syncthreads();
            if (gr < GRP) {                            // 4-deep pipelined gather
                int i = gr;
                for (; i + 3 * GRP < clen; i += 4 * GRP) {
                    int s0 = sS[i], s1 = sS[i + GRP], s2 = sS[i + 2 * GRP], s3 = sS[i + 3 * GRP];
                    float c10 = cf1[i], c11 = cf1[i + GRP], c12 = cf1[i + 2 * GRP], c13 = cf1[i + 3 * GRP];
                    float c20 = cf2[i], c21 = cf2[i + GRP], c22 = cf2[i + 2 * GRP], c23 = cf2[i + 3 * GRP];
                    float v0 = fbase[(size_t)s0 * fstride];
                    float v1 = fbase[(size_t)s1 * fstride];
                    float v2 = fbase[(size_t)s2 * fstride];
                    float v3 = fbase[(size_t)s3 * fstride];
                    a1 += c10 * v0 + c11 * v1 + c12 * v2 + c13 * v3;
                    a2 += c20 * v0 + c21 * v1 + c22 * v2 + c23 * v3;
                }
                for (; i < clen; i += GRP) {
                    float v = fbase[(size_t)sS[i] * fstride];
                    a1 += cf1[i] * v;
                    a2 += cf2[i] * v;
                }
            }
            __syncthreads();
        }
        if (gr < GRP) { tp1[gr][pl] = a1; tp2[gr][pl] = a2; }
        __syncthreads();
        if (tid < PSLICE) {
            float A1 = 0.f, A2 = 0.f;
            #pragma unroll
            for (int g2 = 0; g2 < GRP; ++g2) { A1 += tp1[g2][tid]; A2 += tp2[g2][tid]; }
            int q = qstart + tid;
            int ko = q / fstride;
            float ff0 = fb0[q % fstride];
            tslice[tid] = (ko == 0) ? ff0 : ((ko == 1) ? -A1 : 2.f * A2 - ff0);
        }
        __syncthreads();

        {   // gemv over the block's 12 p-rows; system stores to gpart
            const float* tb = isx ? theta_x : theta_h;
            const size_t gs = isx ? (size_t)(3 * FD) * HDIM : (size_t)(3 * HDIM) * HDIM;
            float g0 = 0.f, g1 = 0.f, g2v = 0.f, g3 = 0.f;
            #pragma unroll
            for (int pp = 0; pp < PSLICE; ++pp) {
                float tv = tslice[pp];
                const float* row = tb + (size_t)(qstart + pp) * HDIM;
                g0  += tv * row[tid];
                g1  += tv * row[gs + tid];
                g2v += tv * row[2 * gs + tid];
                g3  += tv * row[3 * gs + tid];
            }
            float* gp = gpart + (size_t)bid * 1024;
            ssf(&gp[tid], g0);
            ssf(&gp[HDIM + tid], g1);
            ssf(&gp[2 * HDIM + tid], g2v);
            ssf(&gp[3 * HDIM + tid], g3);
        }
        __syncthreads();   // drains vmcnt: this block's gpart stores at LLC
        if (tid == 0)
            __hip_atomic_store(&gdone[bid], 1u, __ATOMIC_RELEASE, __HIP_MEMORY_SCOPE_SYSTEM);
        return;
    }

    // ================== gates block ==================
    const int sbid = bid - GB;

    // poll graph-done flags while the graph still runs (96 parallel pollers)
    if (tid < GB) {
        int sp = 0;
        while (__hip_atomic_load(&gdone[tid], __ATOMIC_RELAXED,
                                 __HIP_MEMORY_SCOPE_SYSTEM) == 0u) {
            if (++sp > SPIN_CAP) break;
        }
    }
    __syncthreads();       // all 96 flags observed -> all gpart data at LLC

    // gpart reduce for this block's 32 gate-dims: d = tid>>3, 8 threads/dim
    {
        const int d = tid >> 3, j = tid & 7;
        const int g = d >> 3, kk = d & 7, o = sbid * 8 + kk;
        float s = 0.f;
        #pragma unroll
        for (int pb = j; pb < GB; pb += 8) s += slf(&gpart[(size_t)pb * 1024 + g * HDIM + o]);
        s += __shfl_down(s, 4);
        s += __shfl_down(s, 2);
        s += __shfl_down(s, 1);
        if (j == 0) sdot[d] = s;
    }
    __syncthreads();

    // gates for this block's 8 dims -> hbuf/cbuf (plain stores; boundary = sync)
    if (tid < 8) {
        const int o = sbid * 8 + tid;
        float g0 = sdot[tid]      + bias_x[o]            + bias_h[o];
        float g1 = sdot[8 + tid]  + bias_x[HDIM + o]     + bias_h[HDIM + o];
        float g2 = sdot[16 + tid] + bias_x[2 * HDIM + o] + bias_h[2 * HDIM + o];
        float g3 = sdot[24 + tid] + bias_x[3 * HDIM + o] + bias_h[3 * HDIM + o];
        float c0 = c[o];
        float I  = sigm(g0 + w_c[o] * c0 + b_gate[o]);
        float Fg = sigm(g1 + w_c[HDIM + o] * c0 + b_gate[HDIM + o]);
        float Cn = Fg * c0 + I * tanhf(g2 + b_gate[2 * HDIM + o]);
        float O  = sigm(g3 + w_c[2 * HDIM + o] * Cn + b_gate[3 * HDIM + o]);
        hbuf[o] = O * tanhf(Cn);
        cbuf[o] = Cn;
    }
}

// Tail: 32 blocks x 256 thr. Plain-load h0/c0 (coherent via boundary), then
// ONLY 7 exchange rounds (h1..h7) using r14's proven contiguous tagged-u64.
__global__ __launch_bounds__(TPB) void k_tail2(
    const float* __restrict__ x,
    const float* __restrict__ w_ih, const float* __restrict__ w_hh,
    const float* __restrict__ b_ih, const float* __restrict__ b_hh,
    const float* __restrict__ w_out, const float* __restrict__ b_out,
    float* __restrict__ out, char* __restrict__ ws) {

    unsigned long long* hsync = (unsigned long long*)(ws + O_HSYNC);
    const float* hbuf = (const float*)(ws + O_HBUF);
    const float* cbuf = (const float*)(ws + O_CBUF);

    __shared__ __align__(16) float sh[HDIM];
    __shared__ float sdot[32];
    __shared__ float swsum[4];

    const int tid = threadIdx.x, bid = blockIdx.x;

    // w_hh rows in VGPRs (proven no-spill layout: 32 rows/block, 8 thr/row)
    const int rl = tid >> 3, seg = tid & 7;
    const int grow = (rl >> 3) * HDIM + bid * 8 + (rl & 7);
    float4 wreg[8];
    #pragma unroll
    for (int k = 0; k < 8; ++k)
        wreg[k] = *(const float4*)&w_hh[(size_t)grow * HDIM + seg * 32 + k * 4];
    const float wih_r = w_ih[grow];
    const float br    = b_ih[grow] + b_hh[grow];
    const float bo    = b_out[0];
    const float wout_r = w_out[tid];

    // h0 via plain loads (kernel boundary made k_fused's stores coherent)
    sh[tid] = hbuf[tid];
    float creg = (tid < 8) ? cbuf[bid * 8 + tid] : 0.f;
    __syncthreads();
    float sinp = x[FD - 1];

    for (int t = 0; t < TT; ++t) {
        // dot on sh = h(t)
        float acc = 0.f;
        const float* shh = &sh[seg * 32];
        #pragma unroll
        for (int k = 0; k < 8; ++k) {
            float4 hv = *(const float4*)&shh[k * 4];
            acc += hv.x * wreg[k].x + hv.y * wreg[k].y + hv.z * wreg[k].z + hv.w * wreg[k].w;
        }
        acc += __shfl_down(acc, 4);
        acc += __shfl_down(acc, 2);
        acc += __shfl_down(acc, 1);
        if (seg == 0) sdot[rl] = acc + sinp * wih_r + br;
        __syncthreads();                        // S1: sh reads done, sdot ready
        if (tid < 8) {
            float iv = sdot[tid], fv = sdot[8 + tid], gv = sdot[16 + tid], ov = sdot[24 + tid];
            float cn = sigm(fv) * creg + sigm(iv) * tanhf(gv);
            float hn = sigm(ov) * tanhf(cn);
            creg = cn;
            unsigned long long pk = (((unsigned long long)(t + 2)) << 32)
                                  | (unsigned long long)__float_as_uint(hn);
            __hip_atomic_store(&hsync[(t + 1) * HDIM + bid * 8 + tid], pk,
                               __ATOMIC_RELAXED, __HIP_MEMORY_SCOPE_SYSTEM);
        }
        // parallel poll: every thread its own h(t+1) word; payload stays in reg
        float hval;
        {
            unsigned long long v;
            int sp = 0;
            do {
                v = __hip_atomic_load(&hsync[(t + 1) * HDIM + tid],
                                      __ATOMIC_RELAXED, __HIP_MEMORY_SCOPE_SYSTEM);
                if ((unsigned)(v >> 32) == (unsigned)(t + 2)) break;
            } while (++sp < SPIN_CAP);
            hval = __uint_as_float((unsigned)v);
        }
        sh[tid] = hval;
        float pw = wout_r * hval;               // out[t] = w_out . h(t+1) + bo
        pw += __shfl_down(pw, 32);
        pw += __shfl_down(pw, 16);
        pw += __shfl_down(pw, 8);
        pw += __shfl_down(pw, 4);
        pw += __shfl_down(pw, 2);
        pw += __shfl_down(pw, 1);
        if ((tid & 63) == 0) swsum[tid >> 6] = pw;
        __syncthreads();                        // S2: swsum + new sh visible
        float sval = swsum[0] + swsum[1] + swsum[2] + swsum[3] + bo;
        sinp = sval;                            // input to step t+1
        if (bid == 0 && tid == 0) out[t] = sval;
    }
}

extern "C" void kernel_launch(void* const* d_in, const int* in_sizes, int n_in,
                              void* d_out, int out_size, void* d_ws, size_t ws_size,
                              hipStream_t stream) {
    const float* x       = (const float*)d_in[0];
    const int*   ei      = (const int*)d_in[1];
    const float* ew      = (const float*)d_in[2];
    const float* h       = (const float*)d_in[3];
    const float* c       = (const float*)d_in[4];
    const float* theta_x = (const float*)d_in[5];
    const float* bias_x  = (const float*)d_in[6];
    const float* theta_h = (const float*)d_in[7];
    const float* bias_h  = (const float*)d_in[8];
    const float* w_c     = (const float*)d_in[9];
    const float* b_gate  = (const float*)d_in[10];
    const float* w_ih    = (const float*)d_in[11];
    const float* w_hh    = (const float*)d_in[12];
    const float* b_ih    = (const float*)d_in[13];
    const float* b_hh    = (const float*)d_in[14];
    const float* w_out   = (const float*)d_in[15];
    const float* b_out   = (const float*)d_in[16];
    char* ws = (char*)d_ws;
    float* out = (float*)d_out;

    hipMemsetAsync(ws, 0, 64, stream);          // nbrCnt; rest zeroed by k_nbr

    int eb4 = (NE / 4 + TPB - 1) / TPB;         // 782 blocks
    k_nbr<<<eb4, TPB, 0, stream>>>(ei, ew, ws);
    k_match<<<eb4, TPB, 0, stream>>>(ei, ew, ws);
    k_deg<<<eb4, TPB, 0, stream>>>(ei, ew, ws);
    k_fused<<<FGRID, TPB, 0, stream>>>(x, h, c, theta_x, bias_x, theta_h, bias_h,
                                       w_c, b_gate, ws);
    k_tail2<<<SB, TPB, 0, stream>>>(x, w_ih, w_hh, b_ih, b_hh, w_out, b_out, out, ws);
}

// Round 21
// 52.689 us; speedup vs baseline: 1.2645x; 1.0408x over previous
//
#include <hip/hip_runtime.h>
#include <math.h>

#define NN 50000
#define FD 128
#define HDIM 256
#define NE 800000
#define NBR_CAP 512
#define M_CAP 8192
#define TT 7
#define TPB 256
#define GB 96              // k_graph blocks: 96 x 12 = 1152 p-values
#define PSLICE 12
#define GRP 21             // gather groups per block (252 threads used)
#define ECHUNK 2048
#define SB 32              // k_tail2 blocks
#define SPIN_CAP 50000000

// ws offsets
#define O_NBRCNT   0       // zeroed by 64-B memset node
#define O_MCNT     64
#define O_HSYNC    128     // (TT+1)*HDIM u64 = 16384 -> 16512
#define O_DEG      16512   // NN f -> 216512
#define O_BITMAP   216512  // 1568 u32 -> 222784
#define O_ZERO_END 222784  // k_nbr zeroes [64, 222784)
#define O_NBRNODE  222784  // NBR_CAP i
#define O_NBRW     224832  // NBR_CAP f
#define O_MS       226880  // M_CAP i
#define O_MD       259648  // M_CAP i
#define O_MW       292416  // M_CAP f -> 325184
#define O_GPART    325184  // GB*1024 f -> 718400 (fully overwritten, no zero)

__device__ __forceinline__ float sigm(float v) { return 1.f / (1.f + expf(-v)); }
__device__ __forceinline__ float dis_of(float dg) {
    return dg > 0.f ? rsqrtf(fmaxf(dg, 1e-20f)) : 0.f;
}

// Scan 1: zero ctrl/hsync/deg/bitmap; collect nbr(0).
__global__ void k_nbr(const int* __restrict__ ei, const float* __restrict__ ew,
                      char* __restrict__ ws) {
    int*   nbrCnt = (int*)(ws + O_NBRCNT);
    int*   nbrNode= (int*)(ws + O_NBRNODE);
    float* nbrW   = (float*)(ws + O_NBRW);

    int gid = blockIdx.x * blockDim.x + threadIdx.x;
    if (gid < (O_ZERO_END - O_MCNT) / 4) ((unsigned*)(ws + O_MCNT))[gid] = 0u;

    int e0 = gid * 4;
    if (e0 >= NE) return;
    int4 d4 = *(const int4*)&ei[NE + e0];
    float4 w4 = *(const float4*)&ew[e0];
    int dd[4] = {d4.x, d4.y, d4.z, d4.w};
    float wv[4] = {w4.x, w4.y, w4.z, w4.w};
    #pragma unroll
    for (int k = 0; k < 4; ++k) {
        if (dd[k] == 0 && wv[k] != 0.f) {
            int s = ei[e0 + k];
            if (s != 0) {
                int slot = atomicAdd(nbrCnt, 1);
                if (slot < NBR_CAP) { nbrNode[slot] = s; nbrW[slot] = wv[k]; }
            }
        }
    }
}

// Scan 2: match edges with d==0 or d in nbr(0); record (s,d,w); mark needed nodes.
__global__ void k_match(const int* __restrict__ ei, const float* __restrict__ ew,
                        char* __restrict__ ws) {
    const int* nbrCnt = (const int*)(ws + O_NBRCNT);
    const int* nbrNode= (const int*)(ws + O_NBRNODE);
    int*      mCnt   = (int*)(ws + O_MCNT);
    int*      mS     = (int*)(ws + O_MS);
    int*      mD     = (int*)(ws + O_MD);
    float*    mW     = (float*)(ws + O_MW);
    unsigned* bitmap = (unsigned*)(ws + O_BITMAP);

    __shared__ int sNode[NBR_CAP];
    __shared__ int sCnt;
    if (threadIdx.x == 0) sCnt = min(*nbrCnt, NBR_CAP);
    __syncthreads();
    int cnt = sCnt;
    for (int i = threadIdx.x; i < cnt; i += blockDim.x) sNode[i] = nbrNode[i];
    __syncthreads();
    if (blockIdx.x == 0 && threadIdx.x == 0) atomicOr(&bitmap[0], 1u);

    int i = blockIdx.x * blockDim.x + threadIdx.x;
    int e0 = i * 4;
    if (e0 >= NE) return;
    int4 s4 = *(const int4*)&ei[e0];
    int4 d4 = *(const int4*)&ei[NE + e0];
    float4 w4 = *(const float4*)&ew[e0];
    int ss[4] = {s4.x, s4.y, s4.z, s4.w};
    int dd[4] = {d4.x, d4.y, d4.z, d4.w};
    float wv[4] = {w4.x, w4.y, w4.z, w4.w};
    bool m[4];
    #pragma unroll
    for (int k = 0; k < 4; ++k) m[k] = (dd[k] == 0);
    for (int j = 0; j < cnt; ++j) {
        int nv = sNode[j];
        #pragma unroll
        for (int k = 0; k < 4; ++k) m[k] |= (dd[k] == nv);
    }
    #pragma unroll
    for (int k = 0; k < 4; ++k) {
        int s = ss[k], d = dd[k];
        float w = wv[k];
        if (s == d || w == 0.f || !m[k]) continue;
        int slot = atomicAdd(mCnt, 1);
        if (slot < M_CAP) { mS[slot] = s; mD[slot] = d; mW[slot] = w; }
        atomicOr(&bitmap[s >> 5], 1u << (s & 31));
        atomicOr(&bitmap[d >> 5], 1u << (d & 31));
    }
}

// Scan 3: deg[s] += w only for bitmap-marked srcs.
__global__ void k_deg(const int* __restrict__ ei, const float* __restrict__ ew,
                      char* __restrict__ ws) {
    const unsigned* bitmap = (const unsigned*)(ws + O_BITMAP);
    float* deg = (float*)(ws + O_DEG);
    int i = blockIdx.x * blockDim.x + threadIdx.x;
    int e0 = i * 4;
    if (e0 >= NE) return;
    int4 s4 = *(const int4*)&ei[e0];
    int4 d4 = *(const int4*)&ei[NE + e0];
    float4 w4 = *(const float4*)&ew[e0];
    int ss[4] = {s4.x, s4.y, s4.z, s4.w};
    int dd[4] = {d4.x, d4.y, d4.z, d4.w};
    float wv[4] = {w4.x, w4.y, w4.z, w4.w};
    #pragma unroll
    for (int k = 0; k < 4; ++k) {
        int s = ss[k];
        if (s == dd[k] || wv[k] == 0.f) continue;
        if (bitmap[s >> 5] & (1u << (s & 31)))
            atomicAdd(&deg[s], wv[k]);
    }
}

// Graph: 96 blocks x 256 thr. Per chunk: inline coef (cheap, overlappable) ->
// 4-deep pipelined gather (21 groups, ~13 edges each). Then tslice + gemv -> gpart.
__global__ __launch_bounds__(TPB) void k_graph(
    const float* __restrict__ x, const float* __restrict__ h,
    const float* __restrict__ theta_x, const float* __restrict__ theta_h,
    char* __restrict__ ws) {

    const float* deg    = (const float*)(ws + O_DEG);
    const int*   nbrCnt = (const int*)(ws + O_NBRCNT);
    const int*   mCnt   = (const int*)(ws + O_MCNT);
    const int*   nbrNode= (const int*)(ws + O_NBRNODE);
    const float* nbrW   = (const float*)(ws + O_NBRW);
    const int*   mS     = (const int*)(ws + O_MS);
    const int*   mD     = (const int*)(ws + O_MD);
    const float* mW     = (const float*)(ws + O_MW);
    float*       gpart  = (float*)(ws + O_GPART);

    __shared__ int   sNode[NBR_CAP];
    __shared__ float sWl[NBR_CAP];
    __shared__ float cf1[ECHUNK], cf2[ECHUNK];
    __shared__ int   sS[ECHUNK];
    __shared__ float tp1[GRP][PSLICE], tp2[GRP][PSLICE];
    __shared__ float tslice[PSLICE];
    __shared__ int   sCnt, sMcnt;

    const int tid = threadIdx.x, bid = blockIdx.x;
    if (tid == 0) { sCnt = min(*nbrCnt, NBR_CAP); sMcnt = min(*mCnt, M_CAP); }
    __syncthreads();
    const int ncnt = sCnt, mcnt = sMcnt;
    for (int i = tid; i < ncnt; i += TPB) { sNode[i] = nbrNode[i]; sWl[i] = nbrW[i]; }
    __syncthreads();

    const bool isx = bid < 32;                         // 384 x-rows, 768 h-rows
    const int qstart = bid * PSLICE - (isx ? 0 : 3 * FD);
    const float* fb0 = isx ? x : h;
    const int fstride = isx ? FD : HDIM;

    const int pl = tid % PSLICE, gr = tid / PSLICE;
    const float* fbase = fb0 + (qstart + pl) % fstride;
    const float dis0 = dis_of(deg[0]);

    float a1 = 0.f, a2 = 0.f;
    for (int c0i = 0; c0i < mcnt; c0i += ECHUNK) {
        int clen = min(ECHUNK, mcnt - c0i);
        for (int i = tid; i < clen; i += TPB) {        // inline per-edge coefs
            int sI = mS[c0i + i], dI = mD[c0i + i];
            float w = mW[c0i + i];
            float disd = dis_of(deg[dI]);
            float wn = dis_of(deg[sI]) * w * disd;
            float Wd = 0.f;
            for (int j = 0; j < ncnt; ++j) Wd += (sNode[j] == dI) ? sWl[j] : 0.f;
            cf1[i] = (dI == 0) ? wn : 0.f;
            cf2[i] = wn * (dis0 * disd * Wd);
            sS[i] = sI;
        }
        __syncthreads();
        if (gr < GRP) {                                // 4-deep pipelined gather
            int i = gr;
            for (; i + 3 * GRP < clen; i += 4 * GRP) {
                int s0 = sS[i], s1 = sS[i + GRP], s2 = sS[i + 2 * GRP], s3 = sS[i + 3 * GRP];
                float c10 = cf1[i], c11 = cf1[i + GRP], c12 = cf1[i + 2 * GRP], c13 = cf1[i + 3 * GRP];
                float c20 = cf2[i], c21 = cf2[i + GRP], c22 = cf2[i + 2 * GRP], c23 = cf2[i + 3 * GRP];
                float v0 = fbase[(size_t)s0 * fstride];
                float v1 = fbase[(size_t)s1 * fstride];
                float v2 = fbase[(size_t)s2 * fstride];
                float v3 = fbase[(size_t)s3 * fstride];
                a1 += c10 * v0 + c11 * v1 + c12 * v2 + c13 * v3;
                a2 += c20 * v0 + c21 * v1 + c22 * v2 + c23 * v3;
            }
            for (; i < clen; i += GRP) {
                float v = fbase[(size_t)sS[i] * fstride];
                a1 += cf1[i] * v;
                a2 += cf2[i] * v;
            }
        }
        __syncthreads();
    }
    if (gr < GRP) { tp1[gr][pl] = a1; tp2[gr][pl] = a2; }
    __syncthreads();
    if (tid < PSLICE) {
        float A1 = 0.f, A2 = 0.f;
        #pragma unroll
        for (int g2 = 0; g2 < GRP; ++g2) { A1 += tp1[g2][tid]; A2 += tp2[g2][tid]; }
        int q = qstart + tid;
        int ko = q / fstride;
        float ff0 = fb0[q % fstride];
        tslice[tid] = (ko == 0) ? ff0 : ((ko == 1) ? -A1 : 2.f * A2 - ff0);
    }
    __syncthreads();

    {   // gemv over the block's 12 p-rows; plain stores to gpart
        const float* tb = isx ? theta_x : theta_h;
        const size_t gs = isx ? (size_t)(3 * FD) * HDIM : (size_t)(3 * HDIM) * HDIM;
        float g0 = 0.f, g1 = 0.f, g2v = 0.f, g3 = 0.f;
        #pragma unroll
        for (int pp = 0; pp < PSLICE; ++pp) {
            float tv = tslice[pp];
            const float* row = tb + (size_t)(qstart + pp) * HDIM;
            g0  += tv * row[tid];
            g1  += tv * row[gs + tid];
            g2v += tv * row[2 * gs + tid];
            g3  += tv * row[3 * gs + tid];
        }
        float* gp = gpart + (size_t)bid * 1024;
        gp[tid] = g0;
        gp[HDIM + tid] = g1;
        gp[2 * HDIM + tid] = g2v;
        gp[3 * HDIM + tid] = g3;
    }
}

// Tail: 32 blocks x 256 thr. gpart reduce -> gates -> 7 steps. Exchange rounds:
// producers (tid<8) store tagged u64; ALL 256 threads busy-poll their own word
// in parallel and keep the payload in a register for the w_out reduce.
__global__ __launch_bounds__(TPB) void k_tail2(
    const float* __restrict__ x, const float* __restrict__ c,
    const float* __restrict__ bias_x, const float* __restrict__ bias_h,
    const float* __restrict__ w_c, const float* __restrict__ b_gate,
    const float* __restrict__ w_ih, const float* __restrict__ w_hh,
    const float* __restrict__ b_ih, const float* __restrict__ b_hh,
    const float* __restrict__ w_out, const float* __restrict__ b_out,
    float* __restrict__ out, char* __restrict__ ws) {

    unsigned long long* hsync = (unsigned long long*)(ws + O_HSYNC);
    const float* gpart = (const float*)(ws + O_GPART);

    __shared__ __align__(16) float sh[HDIM];
    __shared__ float sdot[32];
    __shared__ float swsum[4];

    const int tid = threadIdx.x, bid = blockIdx.x;

    // w_hh rows in VGPRs (proven no-spill layout: 32 rows/block, 8 thr/row)
    const int rl = tid >> 3, seg = tid & 7;
    const int grow = (rl >> 3) * HDIM + bid * 8 + (rl & 7);
    float4 wreg[8];
    #pragma unroll
    for (int k = 0; k < 8; ++k)
        wreg[k] = *(const float4*)&w_hh[(size_t)grow * HDIM + seg * 32 + k * 4];
    const float wih_r = w_ih[grow];
    const float br    = b_ih[grow] + b_hh[grow];
    const float bo    = b_out[0];
    const float wout_r = w_out[tid];

    // gpart reduce for this block's 32 gate-dims: d = tid>>3, 8 threads/dim
    {
        const int d = tid >> 3, j = tid & 7;
        const int g = d >> 3, kk = d & 7, o = bid * 8 + kk;
        float s = 0.f;
        #pragma unroll
        for (int pb = j; pb < GB; pb += 8) s += gpart[(size_t)pb * 1024 + g * HDIM + o];
        s += __shfl_down(s, 4);
        s += __shfl_down(s, 2);
        s += __shfl_down(s, 1);
        if (j == 0) sdot[d] = s;
    }
    __syncthreads();

    // gates -> h0 store (tag 1); c0 in creg
    float creg = 0.f;
    if (tid < 8) {
        const int o = bid * 8 + tid;
        float g0 = sdot[tid]      + bias_x[o]            + bias_h[o];
        float g1 = sdot[8 + tid]  + bias_x[HDIM + o]     + bias_h[HDIM + o];
        float g2 = sdot[16 + tid] + bias_x[2 * HDIM + o] + bias_h[2 * HDIM + o];
        float g3 = sdot[24 + tid] + bias_x[3 * HDIM + o] + bias_h[3 * HDIM + o];
        float c0 = c[o];
        float I  = sigm(g0 + w_c[o] * c0 + b_gate[o]);
        float Fg = sigm(g1 + w_c[HDIM + o] * c0 + b_gate[HDIM + o]);
        float Cn = Fg * c0 + I * tanhf(g2 + b_gate[2 * HDIM + o]);
        float O  = sigm(g3 + w_c[2 * HDIM + o] * Cn + b_gate[3 * HDIM + o]);
        float h0 = O * tanhf(Cn);
        creg = Cn;
        unsigned long long pk = (1ull << 32) | (unsigned long long)__float_as_uint(h0);
        __hip_atomic_store(&hsync[o], pk, __ATOMIC_RELAXED, __HIP_MEMORY_SCOPE_SYSTEM);
    }
    // parallel poll: every thread its own h0 word (busy-spin, no sleep)
    {
        unsigned long long v;
        int sp = 0;
        do {
            v = __hip_atomic_load(&hsync[tid], __ATOMIC_RELAXED, __HIP_MEMORY_SCOPE_SYSTEM);
            if ((unsigned)(v >> 32) == 1u) break;
        } while (++sp < SPIN_CAP);
        sh[tid] = __uint_as_float((unsigned)v);
    }
    __syncthreads();
    float sinp = x[FD - 1];

    for (int t = 0; t < TT; ++t) {
        // dot on sh = h(t)
        float acc = 0.f;
        const float* shh = &sh[seg * 32];
        #pragma unroll
        for (int k = 0; k < 8; ++k) {
            float4 hv = *(const float4*)&shh[k * 4];
            acc += hv.x * wreg[k].x + hv.y * wreg[k].y + hv.z * wreg[k].z + hv.w * wreg[k].w;
        }
        acc += __shfl_down(acc, 4);
        acc += __shfl_down(acc, 2);
        acc += __shfl_down(acc, 1);
        if (seg == 0) sdot[rl] = acc + sinp * wih_r + br;
        __syncthreads();                        // S1: sh reads done, sdot ready
        if (tid < 8) {
            float iv = sdot[tid], fv = sdot[8 + tid], gv = sdot[16 + tid], ov = sdot[24 + tid];
            float cn = sigm(fv) * creg + sigm(iv) * tanhf(gv);
            float hn = sigm(ov) * tanhf(cn);
            creg = cn;
            unsigned long long pk = (((unsigned long long)(t + 2)) << 32)
                                  | (unsigned long long)__float_as_uint(hn);
            __hip_atomic_store(&hsync[(t + 1) * HDIM + bid * 8 + tid], pk,
                               __ATOMIC_RELAXED, __HIP_MEMORY_SCOPE_SYSTEM);
        }
        // parallel poll: every thread its own h(t+1) word; payload stays in reg
        float hval;
        {
            unsigned long long v;
            int sp = 0;
            do {
                v = __hip_atomic_load(&hsync[(t + 1) * HDIM + tid],
                                      __ATOMIC_RELAXED, __HIP_MEMORY_SCOPE_SYSTEM);
                if ((unsigned)(v >> 32) == (unsigned)(t + 2)) break;
            } while (++sp < SPIN_CAP);
            hval = __uint_as_float((unsigned)v);
        }
        sh[tid] = hval;
        float pw = wout_r * hval;               // register payload, no LDS wait
        pw += __shfl_down(pw, 32);
        pw += __shfl_down(pw, 16);
        pw += __shfl_down(pw, 8);
        pw += __shfl_down(pw, 4);
        pw += __shfl_down(pw, 2);
        pw += __shfl_down(pw, 1);
        if ((tid & 63) == 0) swsum[tid >> 6] = pw;
        __syncthreads();                        // S2: swsum + new sh visible
        float sval = swsum[0] + swsum[1] + swsum[2] + swsum[3] + bo;
        sinp = sval;                            // input to step t+1
        if (bid == 0 && tid == 0) out[t] = sval;
    }
}

extern "C" void kernel_launch(void* const* d_in, const int* in_sizes, int n_in,
                              void* d_out, int out_size, void* d_ws, size_t ws_size,
                              hipStream_t stream) {
    const float* x       = (const float*)d_in[0];
    const int*   ei      = (const int*)d_in[1];
    const float* ew      = (const float*)d_in[2];
    const float* h       = (const float*)d_in[3];
    const float* c       = (const float*)d_in[4];
    const float* theta_x = (const float*)d_in[5];
    const float* bias_x  = (const float*)d_in[6];
    const float* theta_h = (const float*)d_in[7];
    const float* bias_h  = (const float*)d_in[8];
    const float* w_c     = (const float*)d_in[9];
    const float* b_gate  = (const float*)d_in[10];
    const float* w_ih    = (const float*)d_in[11];
    const float* w_hh    = (const float*)d_in[12];
    const float* b_ih    = (const float*)d_in[13];
    const float* b_hh    = (const float*)d_in[14];
    const float* w_out   = (const float*)d_in[15];
    const float* b_out   = (const float*)d_in[16];
    char* ws = (char*)d_ws;
    float* out = (float*)d_out;

    hipMemsetAsync(ws, 0, 64, stream);          // nbrCnt; rest zeroed by k_nbr

    int eb4 = (NE / 4 + TPB - 1) / TPB;         // 782 blocks
    k_nbr<<<eb4, TPB, 0, stream>>>(ei, ew, ws);
    k_match<<<eb4, TPB, 0, stream>>>(ei, ew, ws);
    k_deg<<<eb4, TPB, 0, stream>>>(ei, ew, ws);
    k_graph<<<GB, TPB, 0, stream>>>(x, h, theta_x, theta_h, ws);
    k_tail2<<<SB, TPB, 0, stream>>>(x, c, bias_x, bias_h, w_c, b_gate,
                                    w_ih, w_hh, b_ih, b_hh, w_out, b_out, out, ws);
}